// Round 1
// baseline (3250.390 us; speedup 1.0000x reference)
//
#include <hip/hip_runtime.h>
#include <hip/hip_bf16.h>

typedef __hip_bfloat16 bf16;

#define PER_B     6291456            // 96*65536
#define S_EL      25165824u          // 4*PER_B
#define EPS_F     1e-5f
#define SCALE_F   0.17677669529663687f   // 32^-0.5
#define LOGIT_MAX_F 4.605170185988092f   // log(100)

__device__ __forceinline__ float b2f(bf16 v){ return __bfloat162float(v); }
__device__ __forceinline__ bf16  f2b(float v){ return __float2bfloat16(v); }

// DT=0: buffers are bf16.  DT=1: buffers are fp32.
template<int DT> __device__ __forceinline__ float rdf(const void* p, size_t i){
  return DT ? ((const float*)p)[i] : b2f(((const bf16*)p)[i]);
}
template<int DT> __device__ __forceinline__ void wrf(void* p, size_t i, float v){
  if (DT) ((float*)p)[i] = v; else ((bf16*)p)[i] = f2b(v);
}
// paired weight load (i must be even)
template<int DT> __device__ __forceinline__ float2 rd2(const void* p, size_t i){
  if (DT) return *(const float2*)((const float*)p + i);
  unsigned u = *(const unsigned*)((const bf16*)p + i);
  return make_float2(__uint_as_float(u << 16), __uint_as_float(u & 0xffff0000u));
}

// ---------- MFMA helpers ----------
typedef __attribute__((ext_vector_type(8))) short short8v;   // 8 bf16 (4 VGPRs)
typedef __attribute__((ext_vector_type(4))) short short4v;
typedef __attribute__((ext_vector_type(4))) float f32x4;

// fp32 -> bf16 bits, round-to-nearest-even (finite inputs)
__device__ __forceinline__ short f2bs(float v){
  unsigned u = __float_as_uint(v);
  return (short)((u + 0x7fffu + ((u >> 16) & 1u)) >> 16);
}
__device__ __forceinline__ float bs2f(short s){
  return __uint_as_float(((unsigned)(unsigned short)s) << 16);
}

// load 8 contiguous weights (elements i..i+8) as bf16 bits; i % 8 == 0
template<int DT> __device__ __forceinline__ short8v ld8(const void* p, size_t i){
  short8v a;
  if (DT){
    const float* f = (const float*)p + i;
    float4 lo = *(const float4*)f;
    float4 hi = *(const float4*)(f + 4);
    a[0]=f2bs(lo.x); a[1]=f2bs(lo.y); a[2]=f2bs(lo.z); a[3]=f2bs(lo.w);
    a[4]=f2bs(hi.x); a[5]=f2bs(hi.y); a[6]=f2bs(hi.z); a[7]=f2bs(hi.w);
  } else {
    a = *(const short8v*)((const short*)p + i);
  }
  return a;
}
// load two 4-element chunks at i0 and i0+16 (elements); i0 % 4 == 0
template<int DT> __device__ __forceinline__ short8v ld4x2(const void* p, size_t i0){
  short8v a;
  if (DT){
    const float* f = (const float*)p;
    float4 lo = *(const float4*)(f + i0);
    float4 hi = *(const float4*)(f + i0 + 16);
    a[0]=f2bs(lo.x); a[1]=f2bs(lo.y); a[2]=f2bs(lo.z); a[3]=f2bs(lo.w);
    a[4]=f2bs(hi.x); a[5]=f2bs(hi.y); a[6]=f2bs(hi.z); a[7]=f2bs(hi.w);
  } else {
    const short* s = (const short*)p;
    short4v lo = *(const short4v*)(s + i0);
    short4v hi = *(const short4v*)(s + i0 + 16);
    a[0]=lo[0]; a[1]=lo[1]; a[2]=lo[2]; a[3]=lo[3];
    a[4]=hi[0]; a[5]=hi[1]; a[6]=hi[2]; a[7]=hi[3];
  }
  return a;
}

// ---------- K0: dtype detector ----------
__global__ __launch_bounds__(256) void k_detect(const void* __restrict__ x, int* __restrict__ flag){
  __shared__ int cnt;
  if (threadIdx.x == 0) cnt = 0;
  __syncthreads();
  float v = b2f(((const bf16*)x)[(size_t)threadIdx.x * 16]);
  int bad = (!(v == v)) || (fabsf(v) > 1e20f);
  if (bad) atomicAdd(&cnt, 1);
  __syncthreads();
  if (threadIdx.x == 0) *flag = (cnt >= 4) ? 1 : 0;
}

// ---------- K1: per-batch partial sums ----------
template<int DT>
__global__ __launch_bounds__(256) void k_stats_partial(const void* __restrict__ x,
    float* __restrict__ partials, const int* __restrict__ flag){
  if (*flag != DT) return;
  int blk = blockIdx.x;
  int b = blk >> 8, chunk = blk & 255;
  const int chunkN = PER_B / 256;
  size_t base = (size_t)b * PER_B + (size_t)chunk * chunkN;
  float s = 0.f, ss = 0.f;
  for (int i = threadIdx.x; i < chunkN; i += 256){
    float v = rdf<DT>(x, base + i); s += v; ss += v*v;
  }
  __shared__ float sh[512];
  sh[threadIdx.x] = s; sh[256 + threadIdx.x] = ss;
  __syncthreads();
  for (int st = 128; st > 0; st >>= 1){
    if (threadIdx.x < st){
      sh[threadIdx.x]     += sh[threadIdx.x + st];
      sh[256+threadIdx.x] += sh[256+threadIdx.x + st];
    }
    __syncthreads();
  }
  if (threadIdx.x == 0){ partials[blk*2] = sh[0]; partials[blk*2+1] = sh[256]; }
}

// ---------- K2: finalize mean/std + rescale/rebias ----------
// stats: [0..3]=mean, [4..7]=std, [8..391]=rescale[b*96+c], [392..775]=rebias
template<int DT>
__global__ __launch_bounds__(256) void k_stats_final(const float* __restrict__ partials,
    const void* m1w, const void* m1b, const void* m2w, const void* m2b,
    float* __restrict__ stats, const int* __restrict__ flag){
  if (*flag != DT) return;
  __shared__ float sh[512];
  __shared__ float mS[4], sS[4];
  for (int b = 0; b < 4; b++){
    sh[threadIdx.x]     = partials[(b*256+threadIdx.x)*2];
    sh[256+threadIdx.x] = partials[(b*256+threadIdx.x)*2+1];
    __syncthreads();
    for (int st = 128; st > 0; st >>= 1){
      if (threadIdx.x < st){
        sh[threadIdx.x]     += sh[threadIdx.x + st];
        sh[256+threadIdx.x] += sh[256+threadIdx.x + st];
      }
      __syncthreads();
    }
    if (threadIdx.x == 0){
      float mean = sh[0] / (float)PER_B;
      float var  = sh[256] / (float)PER_B - mean*mean;
      float stdv = sqrtf(var + EPS_F);
      mS[b] = mean; sS[b] = stdv;
      stats[b] = mean; stats[4+b] = stdv;
    }
    __syncthreads();
  }
  for (int t = threadIdx.x; t < 384; t += 256){
    int b = t / 96, c = t % 96;
    stats[8+t]   = sS[b]*rdf<DT>(m1w,c) + rdf<DT>(m1b,c);
    stats[392+t] = mS[b]*rdf<DT>(m2w,c) + rdf<DT>(m2b,c);
  }
}

// ---------- K3: rel-pos bias table, transposed [h][m][n] ----------
template<int DT>
__global__ __launch_bounds__(256) void k_bias(const void* w1, const void* b1v,
    const void* w2, const void* b2v, float* __restrict__ biasT, const int* __restrict__ flag){
  if (*flag != DT) return;
  int i = blockIdx.x >> 6, j = blockIdx.x & 63;   // i = query n, j = key m
  int dy = (i>>3) - (j>>3), dx = (i&7) - (j&7);
  float fy = (float)dy, fx = (float)dx;
  float r0 = copysignf(log1pf(fabsf(fy)), fy);
  float r1 = copysignf(log1pf(fabsf(fx)), fx);
  int t = threadIdx.x;
  float hb = fmaxf(r0*rdf<DT>(w1,t*2) + r1*rdf<DT>(w1,t*2+1) + rdf<DT>(b1v,t), 0.f);
  __shared__ float sh[256];
  for (int h = 0; h < 3; h++){
    sh[t] = hb * rdf<DT>(w2, h*256+t);
    __syncthreads();
    for (int st = 128; st > 0; st >>= 1){ if (t < st) sh[t] += sh[t+st]; __syncthreads(); }
    if (t == 0) biasT[h*4096 + j*64 + i] = sh[0] + rdf<DT>(b2v, h);
    __syncthreads();
  }
}

// ---------- K4: fused AGN: x -> xn2 (bf16) ----------
template<int DT>
__global__ __launch_bounds__(256) void k_agn_fused(const void* __restrict__ x,
    const float* __restrict__ stats,
    const void* la1w, const void* la1b, const void* la2w, const void* la2b,
    const void* ta1w, const void* ta1b, const void* ta2w, const void* ta2b,
    const void* agnw, const void* agnb,
    bf16* __restrict__ xn2, const int* __restrict__ flag){
  if (*flag != DT) return;
  __shared__ float xs[400];   // 20x20 zero-padded
  __shared__ float ts[324];   // 18x18
  __shared__ float us[324];
  int idx = blockIdx.x;
  int tile = idx & 255; int bc = idx >> 8; int c = bc % 96; int b = bc / 96;
  int oy = (tile >> 4) << 4, ox = (tile & 15) << 4;
  float mean = stats[b], sd = stats[4+b];
  size_t xbase = ((size_t)bc) << 16;
  for (int it = threadIdx.x; it < 400; it += 256){
    int ly = it / 20, lx = it % 20;
    int gy = oy - 2 + ly, gx = ox - 2 + lx;
    float v = 0.f;
    if (gy >= 0 && gy < 256 && gx >= 0 && gx < 256)
      v = (rdf<DT>(x, xbase + (gy<<8) + gx) - mean) / sd;
    xs[it] = v;
  }
  float wl1[9], wt1[9], wl2[9], wt2[9];
  #pragma unroll
  for (int k = 0; k < 9; k++){
    wl1[k] = rdf<DT>(la1w, c*9+k); wt1[k] = rdf<DT>(ta1w, c*9+k);
    wl2[k] = rdf<DT>(la2w, c*9+k); wt2[k] = rdf<DT>(ta2w, c*9+k);
  }
  float bl1 = rdf<DT>(la1b, c), bt1 = rdf<DT>(ta1b, c);
  __syncthreads();
  for (int it = threadIdx.x; it < 324; it += 256){
    int ly = it / 18, lx = it % 18;
    int cy = oy - 1 + ly, cx = ox - 1 + lx;
    float a1 = 0.f, a2 = 0.f;
    if (cy >= 0 && cy < 256 && cx >= 0 && cx < 256){
      a1 = bl1; a2 = bt1;
      #pragma unroll
      for (int dy = 0; dy < 3; dy++)
        #pragma unroll
        for (int dx = 0; dx < 3; dx++){
          float v = xs[(ly+dy)*20 + lx+dx];
          a1 += v * wl1[dy*3+dx]; a2 += v * wt1[dy*3+dx];
        }
      a1 = fmaxf(a1, 0.f); a2 = fmaxf(a2, 0.f);
    }
    ts[it] = a1; us[it] = a2;
  }
  __syncthreads();
  int ty = threadIdx.x >> 4, tx0 = threadIdx.x & 15;
  float l = rdf<DT>(la2b, c), t = rdf<DT>(ta2b, c);
  #pragma unroll
  for (int dy = 0; dy < 3; dy++)
    #pragma unroll
    for (int dx = 0; dx < 3; dx++){
      l += ts[(ty+dy)*18 + tx0+dx] * wl2[dy*3+dx];
      t += us[(ty+dy)*18 + tx0+dx] * wt2[dy*3+dx];
    }
  float v = xs[(ty+2)*20 + tx0+2];
  float r = v*(rdf<DT>(agnw,c)*stats[8+bc]) + (rdf<DT>(agnb,c) + stats[392+bc]) + l + t;
  xn2[xbase + ((oy+ty)<<8) + ox + tx0] = f2b(r);
}

// ---------- K5: mega window kernel, transposed conflict-free LDS ----------
// Arena 64512 B, all tiles [channel][pixel] with pixel = lane index:
//  [0,27648)      xs[96][144] -> xc[96][64] @[0,12288) -> cs[96][64] @[0,12288)
//  [12288,24576)  Ks[96][64]  (written after xs compacted)
//  [24576,36864)  Vs[96][64]
//  [36864,64512)  Qs[96][144] -> os[96][64]f32 @[36864,61440) after dw5
template<int DT>
__global__ __launch_bounds__(256) void k_attn_mega(const bf16* __restrict__ xn2,
    const void* qw, const void* qb, const void* kvw, const void* kvb,
    const void* dww, const void* dwb, const void* pw, const void* pb,
    const void* lsin, const float* __restrict__ biasT,
    const void* __restrict__ xin, const float* __restrict__ stats,
    void* __restrict__ outp, const int* __restrict__ flag){
  if (*flag != DT) return;
  __shared__ __align__(16) char smem[64512];
  bf16*  xs = (bf16*)smem;              // [96][144]
  bf16*  xc = (bf16*)smem;              // [96][64] compacted
  bf16*  cs = (bf16*)smem;              // [96][64] (xc dead after KV)
  bf16*  Ks = (bf16*)(smem + 12288);    // [96][64]
  bf16*  Vs = (bf16*)(smem + 24576);    // [96][64]
  bf16*  Qs = (bf16*)(smem + 36864);    // [96][144]
  float* os = (float*)(smem + 36864);   // [96][64] f32 (Qs dead after dw5)
  int tid = threadIdx.x, wid = blockIdx.x;
  int b = wid >> 10, wy = (wid >> 5) & 31, wx = wid & 31;
  int wv = tid >> 6, ln = tid & 63;

  // 1. stage xn2 reflected 12x12 halo -> xs[c][t]
  for (int it = tid; it < 13824; it += 256){
    int t = it % 144, c = it / 144;
    int ty = (wy<<3) - 2 + t/12, tx = (wx<<3) - 2 + t%12;
    ty = ty < 0 ? -ty : (ty > 255 ? 510 - ty : ty);
    tx = tx < 0 ? -tx : (tx > 255 ? 510 - tx : tx);
    xs[c*144 + t] = xn2[(((size_t)(b*96 + c))<<16) + (ty<<8) + tx];
  }
  __syncthreads();

  // 2. Q at 144 positions: wave owns 24 oc; 3 pixels/lane share each weight pair
  for (int ocb = 0; ocb < 24; ocb++){
    int oc = wv*24 + ocb;
    size_t wb = (size_t)oc*96;
    float a0 = 0.f, a1 = 0.f, a2 = 0.f;
    #pragma unroll 4
    for (int c = 0; c < 96; c += 2){
      float2 w = rd2<DT>(qw, wb + c);
      const bf16* r0 = xs + c*144;
      const bf16* r1 = xs + (c+1)*144;
      a0 += w.x * b2f(r0[ln]);
      a1 += w.x * b2f(r0[64 + ln]);
      a2 += w.x * b2f(r0[128 + (ln & 15)]);
      a0 += w.y * b2f(r1[ln]);
      a1 += w.y * b2f(r1[64 + ln]);
      a2 += w.y * b2f(r1[128 + (ln & 15)]);
    }
    float qbv = rdf<DT>(qb, oc);
    Qs[oc*144 + ln]      = f2b(a0 + qbv);
    Qs[oc*144 + 64 + ln] = f2b(a1 + qbv);
    if (ln < 16) Qs[oc*144 + 128 + ln] = f2b(a2 + qbv);
  }
  __syncthreads();

  // 3. compact xs centers -> xc[c][n] (reg-buffered, regions overlap)
  {
    bf16 tmp[24];
    #pragma unroll
    for (int k = 0; k < 24; k++){
      int it = tid + k*256;
      int n = it & 63, c = it >> 6;
      int t = ((n>>3)+2)*12 + (n&7) + 2;
      tmp[k] = xs[c*144 + t];
    }
    __syncthreads();
    #pragma unroll
    for (int k = 0; k < 24; k++){
      int it = tid + k*256;
      int n = it & 63, c = it >> 6;
      xc[c*64 + n] = tmp[k];
    }
  }
  __syncthreads();

  // 4. K (x SCALE) and V: wave owns 48 oc, lane = pixel
  for (int ocb = 0; ocb < 48; ocb++){
    int oc = wv*48 + ocb;
    size_t wb = (size_t)oc*96;
    float a = 0.f;
    #pragma unroll 4
    for (int c = 0; c < 96; c += 2){
      float2 w = rd2<DT>(kvw, wb + c);
      a += w.x * b2f(xc[c*64 + ln]);
      a += w.y * b2f(xc[(c+1)*64 + ln]);
    }
    a += rdf<DT>(kvb, oc);
    if (oc < 96) Ks[oc*64 + ln] = f2b(a * SCALE_F);
    else         Vs[(oc-96)*64 + ln] = f2b(a);
  }
  __syncthreads();

  // 5. 5x5 dwconv on Q -> cs[c][n]: wave owns 24 channels, lane = pixel
  {
    int ty0 = (ln>>3)+2, tx0 = (ln&7)+2;
    for (int cb = 0; cb < 24; cb++){
      int c = wv*24 + cb;
      float a = rdf<DT>(dwb, c);
      const bf16* Qrow = Qs + c*144;
      #pragma unroll
      for (int dy = -2; dy <= 2; dy++)
        #pragma unroll
        for (int dx = -2; dx <= 2; dx++)
          a += b2f(Qrow[(ty0+dy)*12 + tx0+dx]) * rdf<DT>(dww, c*25 + (dy+2)*5 + dx+2);
      cs[c*64 + ln] = f2b(a);
    }
  }
  __syncthreads();

  // 6. attention: wave = head, lane = token; K/V reads are lane-broadcast
  if (tid < 192){
    int h = wv, n = ln;
    float q[32];
    #pragma unroll
    for (int d = 0; d < 32; d++) q[d] = b2f(cs[(h*32 + d)*64 + n]);
    float ls = __expf(fminf(rdf<DT>(lsin, 0), LOGIT_MAX_F));
    const float* bh = biasT + h*4096 + n;
    float mx = -3e38f, s = 0.f;
    float o[32];
    #pragma unroll
    for (int d = 0; d < 32; d++) o[d] = 0.f;
    for (int m = 0; m < 64; m++){
      float c0=0.f,c1=0.f,c2=0.f,c3=0.f;
      #pragma unroll
      for (int d = 0; d < 32; d += 4){
        c0 += q[d  ]*b2f(Ks[(h*32+d  )*64 + m]);
        c1 += q[d+1]*b2f(Ks[(h*32+d+1)*64 + m]);
        c2 += q[d+2]*b2f(Ks[(h*32+d+2)*64 + m]);
        c3 += q[d+3]*b2f(Ks[(h*32+d+3)*64 + m]);
      }
      float l = (c0+c1+c2+c3)*ls + bh[m*64];
      float nm = fmaxf(mx, l);
      float corr = __expf(mx - nm);
      float p = __expf(l - nm);
      s = s*corr + p;
      #pragma unroll
      for (int d = 0; d < 32; d++) o[d] = o[d]*corr + p*b2f(Vs[(h*32+d)*64 + m]);
      mx = nm;
    }
    float inv = 1.f / s;
    #pragma unroll
    for (int d = 0; d < 32; d++) os[(h*32 + d)*64 + n] = o[d]*inv;
  }
  __syncthreads();

  // 7. proj + residual -> out: wave owns 24 oc, lane = pixel
  for (int ocb = 0; ocb < 24; ocb++){
    int oc = wv*24 + ocb;
    size_t wb = (size_t)oc*96;
    float a = 0.f;
    #pragma unroll 4
    for (int c = 0; c < 96; c += 2){
      float2 w = rd2<DT>(pw, wb + c);
      a += w.x * os[c*64 + ln];
      a += w.y * os[(c+1)*64 + ln];
    }
    a += rdf<DT>(pb, oc);
    int gy = (wy<<3) + (ln>>3), gx = (wx<<3) + (ln&8-8+(ln&7));
    gx = (wx<<3) + (ln&7);
    size_t gi = (((size_t)(b*96 + oc))<<16) + (gy<<8) + gx;
    float x1 = rdf<DT>(xin, gi) + a*stats[8 + b*96 + oc] + stats[392 + b*96 + oc];
    wrf<DT>(outp, gi, x1);
  }
}

// ---------- K6: MFMA MLP in-place on d_out ----------
// Block = 64 contiguous pixels of one batch, 4 waves; wave = 16 pixels.
// GEMM1: H[384,64] = relu(W1[384,96] @ X[96,64] + b1), H kept in registers as
//        GEMM2 B-fragments (D-layout col=lane&15 == B-layout col=lane&15).
// GEMM2: Y[96,64] = X + W2[96,384] @ H + b2.
// k-permutation per fragment is applied identically to A and B operands, so
// the MFMA reduction is a permuted (= equal) sum.
template<int DT>
__global__ __launch_bounds__(256) void k_mlp_mfma(void* __restrict__ io,
    const void* w1, const void* b1, const void* w2, const void* b2v,
    const int* __restrict__ flag){
  if (*flag != DT) return;
  __shared__ short x1s[64*104];   // [pixel][channel], pad 96->104 (16B-mult row)
  int blk = blockIdx.x; int b = blk >> 10; int pix0 = (blk & 1023) << 6;
  int tid = threadIdx.x;
  // stage X transposed (coalesced global read, scattered u16 LDS write)
  for (int it = tid; it < 6144; it += 256){
    int c = it >> 6, p = it & 63;
    size_t gi = (((size_t)(b*96 + c))<<16) + pix0 + p;
    short v = DT ? f2bs(((const float*)io)[gi]) : ((const short*)io)[gi];
    x1s[p*104 + c] = v;
  }
  __syncthreads();

  int w = tid >> 6, l = tid & 63;
  int r = l & 15, q = l >> 4;
  int pw = w << 4;                       // wave's pixel base within tile

  // B-fragments for GEMM1: X[32kt+8q+i][pw+r], one ds_read_b128 each
  short8v B1[3];
  #pragma unroll
  for (int kt = 0; kt < 3; kt++)
    B1[kt] = *(const short8v*)&x1s[(pw + r)*104 + 32*kt + 8*q];

  // GEMM1: 24 M-tiles (paired), pack D directly into GEMM2 B-fragments
  short8v B2[12];
  #pragma unroll
  for (int t = 0; t < 12; t++){
    f32x4 accA = {0.f,0.f,0.f,0.f};
    f32x4 accB = {0.f,0.f,0.f,0.f};
    #pragma unroll
    for (int kt = 0; kt < 3; kt++){
      short8v aA = ld8<DT>(w1, (size_t)(32*t + r)*96      + 32*kt + 8*q);
      short8v aB = ld8<DT>(w1, (size_t)(32*t + 16 + r)*96 + 32*kt + 8*q);
      accA = __builtin_amdgcn_mfma_f32_16x16x32_bf16(aA, B1[kt], accA, 0, 0, 0);
      accB = __builtin_amdgcn_mfma_f32_16x16x32_bf16(aB, B1[kt], accB, 0, 0, 0);
    }
    short8v h;
    #pragma unroll
    for (int j = 0; j < 4; j++){
      float hA = accA[j] + rdf<DT>(b1, 32*t + 4*q + j);
      float hB = accB[j] + rdf<DT>(b1, 32*t + 16 + 4*q + j);
      h[j]   = f2bs(fmaxf(hA, 0.f));    // lane holds H[32t+4q+j][pw+r]
      h[4+j] = f2bs(fmaxf(hB, 0.f));    // lane holds H[32t+16+4q+j][pw+r]
    }
    B2[t] = h;
  }

  // GEMM2: A-fragment k-map matches B2 pack: k = 32t+4q+i (i<4), +16 (i>=4)
  for (int mt = 0; mt < 6; mt++){
    f32x4 acc = {0.f,0.f,0.f,0.f};
    #pragma unroll
    for (int t = 0; t < 12; t++){
      short8v a = ld4x2<DT>(w2, (size_t)(16*mt + r)*384 + 32*t + 4*q);
      acc = __builtin_amdgcn_mfma_f32_16x16x32_bf16(a, B2[t], acc, 0, 0, 0);
    }
    #pragma unroll
    for (int j = 0; j < 4; j++){
      int oc = 16*mt + 4*q + j;
      size_t gi = (((size_t)(b*96 + oc))<<16) + pix0 + pw + r;
      wrf<DT>(io, gi, rdf<DT>(io, gi) + acc[j] + rdf<DT>(b2v, oc));
    }
  }
}

extern "C" void kernel_launch(void* const* d_in, const int* in_sizes, int n_in,
                              void* d_out, int out_size, void* d_ws, size_t ws_size,
                              hipStream_t stream) {
  const void* x      = d_in[0];
  const void* agnw   = d_in[1];
  const void* agnb   = d_in[2];
  const void* meta1w = d_in[3];
  const void* meta1b = d_in[4];
  const void* meta2w = d_in[5];
  const void* meta2b = d_in[6];
  const void* la1w   = d_in[7];
  const void* la1b   = d_in[8];
  const void* la2w   = d_in[9];
  const void* la2b   = d_in[10];
  const void* ta1w   = d_in[11];
  const void* ta1b   = d_in[12];
  const void* ta2w   = d_in[13];
  const void* ta2b   = d_in[14];
  const void* qw     = d_in[15];
  const void* qb     = d_in[16];
  const void* kvw    = d_in[17];
  const void* kvb    = d_in[18];
  const void* dww    = d_in[19];
  const void* dwb    = d_in[20];
  const void* pw     = d_in[21];
  const void* pb     = d_in[22];
  const void* lsin   = d_in[23];
  const void* rpw1   = d_in[24];
  const void* rpb1   = d_in[25];
  const void* rpw2   = d_in[26];
  const void* rpb2   = d_in[27];
  const void* m1w    = d_in[28];
  const void* m1b    = d_in[29];
  const void* m2w    = d_in[30];
  const void* m2b    = d_in[31];

  // ws: flag @0 | partials @256 | stats @8448 | biasT @12288 | xn2 @65536 (48MB)
  char* ws = (char*)d_ws;
  int*   flag     = (int*)ws;
  float* partials = (float*)(ws + 256);
  float* stats    = (float*)(ws + 8448);
  float* biasT    = (float*)(ws + 12288);
  bf16*  xn2      = (bf16*)(ws + 65536);

  k_detect<<<1, 256, 0, stream>>>(x, flag);

  // bf16 variant
  k_stats_partial<0><<<1024, 256, 0, stream>>>(x, partials, flag);
  k_stats_final<0>  <<<1,    256, 0, stream>>>(partials, meta1w, meta1b, meta2w, meta2b, stats, flag);
  k_bias<0>         <<<4096, 256, 0, stream>>>(rpw1, rpb1, rpw2, rpb2, biasT, flag);
  k_agn_fused<0>    <<<98304,256, 0, stream>>>(x, stats, la1w, la1b, la2w, la2b,
                                               ta1w, ta1b, ta2w, ta2b, agnw, agnb, xn2, flag);
  k_attn_mega<0>    <<<4096, 256, 0, stream>>>(xn2, qw, qb, kvw, kvb, dww, dwb, pw, pb,
                                               lsin, biasT, x, stats, d_out, flag);
  k_mlp_mfma<0>     <<<4096, 256, 0, stream>>>(d_out, m1w, m1b, m2w, m2b, flag);

  // fp32 variant
  k_stats_partial<1><<<1024, 256, 0, stream>>>(x, partials, flag);
  k_stats_final<1>  <<<1,    256, 0, stream>>>(partials, meta1w, meta1b, meta2w, meta2b, stats, flag);
  k_bias<1>         <<<4096, 256, 0, stream>>>(rpw1, rpb1, rpw2, rpb2, biasT, flag);
  k_agn_fused<1>    <<<98304,256, 0, stream>>>(x, stats, la1w, la1b, la2w, la2b,
                                               ta1w, ta1b, ta2w, ta2b, agnw, agnb, xn2, flag);
  k_attn_mega<1>    <<<4096, 256, 0, stream>>>(xn2, qw, qb, kvw, kvb, dww, dwb, pw, pb,
                                               lsin, biasT, x, stats, d_out, flag);
  k_mlp_mfma<1>     <<<4096, 256, 0, stream>>>(d_out, m1w, m1b, m2w, m2b, flag);
}

// Round 2
// 1439.723 us; speedup vs baseline: 2.2577x; 2.2577x over previous
//
#include <hip/hip_runtime.h>
#include <hip/hip_bf16.h>

typedef __hip_bfloat16 bf16;

#define PER_B     6291456            // 96*65536
#define EPS_F     1e-5f
#define SCALE_F   0.17677669529663687f   // 32^-0.5
#define LOGIT_MAX_F 4.605170185988092f   // log(100)

__device__ __forceinline__ float b2f(bf16 v){ return __bfloat162float(v); }
__device__ __forceinline__ bf16  f2b(float v){ return __float2bfloat16(v); }

// DT=0: buffers are bf16.  DT=1: buffers are fp32.
template<int DT> __device__ __forceinline__ float rdf(const void* p, size_t i){
  return DT ? ((const float*)p)[i] : b2f(((const bf16*)p)[i]);
}
template<int DT> __device__ __forceinline__ void wrf(void* p, size_t i, float v){
  if (DT) ((float*)p)[i] = v; else ((bf16*)p)[i] = f2b(v);
}
// paired weight load (i must be even)
template<int DT> __device__ __forceinline__ float2 rd2(const void* p, size_t i){
  if (DT) return *(const float2*)((const float*)p + i);
  unsigned u = *(const unsigned*)((const bf16*)p + i);
  return make_float2(__uint_as_float(u << 16), __uint_as_float(u & 0xffff0000u));
}

// ---------- MFMA helpers ----------
typedef __attribute__((ext_vector_type(8))) short short8v;   // 8 bf16 (4 VGPRs)
typedef __attribute__((ext_vector_type(4))) short short4v;
typedef __attribute__((ext_vector_type(4))) float f32x4;

// fp32 -> bf16 bits, round-to-nearest-even (finite inputs)
__device__ __forceinline__ short f2bs(float v){
  unsigned u = __float_as_uint(v);
  return (short)((u + 0x7fffu + ((u >> 16) & 1u)) >> 16);
}
__device__ __forceinline__ float bs2f(short s){
  return __uint_as_float(((unsigned)(unsigned short)s) << 16);
}

// load 8 contiguous weights (elements i..i+8) as bf16 bits; i % 8 == 0
template<int DT> __device__ __forceinline__ short8v ld8(const void* p, size_t i){
  short8v a;
  if (DT){
    const float* f = (const float*)p + i;
    float4 lo = *(const float4*)f;
    float4 hi = *(const float4*)(f + 4);
    a[0]=f2bs(lo.x); a[1]=f2bs(lo.y); a[2]=f2bs(lo.z); a[3]=f2bs(lo.w);
    a[4]=f2bs(hi.x); a[5]=f2bs(hi.y); a[6]=f2bs(hi.z); a[7]=f2bs(hi.w);
  } else {
    a = *(const short8v*)((const short*)p + i);
  }
  return a;
}
// load two 4-element chunks at i0 and i0+16 (elements); i0 % 4 == 0
template<int DT> __device__ __forceinline__ short8v ld4x2(const void* p, size_t i0){
  short8v a;
  if (DT){
    const float* f = (const float*)p;
    float4 lo = *(const float4*)(f + i0);
    float4 hi = *(const float4*)(f + i0 + 16);
    a[0]=f2bs(lo.x); a[1]=f2bs(lo.y); a[2]=f2bs(lo.z); a[3]=f2bs(lo.w);
    a[4]=f2bs(hi.x); a[5]=f2bs(hi.y); a[6]=f2bs(hi.z); a[7]=f2bs(hi.w);
  } else {
    const short* s = (const short*)p;
    short4v lo = *(const short4v*)(s + i0);
    short4v hi = *(const short4v*)(s + i0 + 16);
    a[0]=lo[0]; a[1]=lo[1]; a[2]=lo[2]; a[3]=lo[3];
    a[4]=hi[0]; a[5]=hi[1]; a[6]=hi[2]; a[7]=hi[3];
  }
  return a;
}

// ---------- K0: dtype detector ----------
__global__ __launch_bounds__(256) void k_detect(const void* __restrict__ x, int* __restrict__ flag){
  __shared__ int cnt;
  if (threadIdx.x == 0) cnt = 0;
  __syncthreads();
  float v = b2f(((const bf16*)x)[(size_t)threadIdx.x * 16]);
  int bad = (!(v == v)) || (fabsf(v) > 1e20f);
  if (bad) atomicAdd(&cnt, 1);
  __syncthreads();
  if (threadIdx.x == 0) *flag = (cnt >= 4) ? 1 : 0;
}

// ---------- K1: per-batch partial sums ----------
template<int DT>
__global__ __launch_bounds__(256) void k_stats_partial(const void* __restrict__ x,
    float* __restrict__ partials, const int* __restrict__ flag){
  if (*flag != DT) return;
  int blk = blockIdx.x;
  int b = blk >> 8, chunk = blk & 255;
  const int chunkN = PER_B / 256;
  size_t base = (size_t)b * PER_B + (size_t)chunk * chunkN;
  float s = 0.f, ss = 0.f;
  for (int i = threadIdx.x; i < chunkN; i += 256){
    float v = rdf<DT>(x, base + i); s += v; ss += v*v;
  }
  __shared__ float sh[512];
  sh[threadIdx.x] = s; sh[256 + threadIdx.x] = ss;
  __syncthreads();
  for (int st = 128; st > 0; st >>= 1){
    if (threadIdx.x < st){
      sh[threadIdx.x]     += sh[threadIdx.x + st];
      sh[256+threadIdx.x] += sh[256+threadIdx.x + st];
    }
    __syncthreads();
  }
  if (threadIdx.x == 0){ partials[blk*2] = sh[0]; partials[blk*2+1] = sh[256]; }
}

// ---------- K2: finalize mean/std + rescale/rebias ----------
template<int DT>
__global__ __launch_bounds__(256) void k_stats_final(const float* __restrict__ partials,
    const void* m1w, const void* m1b, const void* m2w, const void* m2b,
    float* __restrict__ stats, const int* __restrict__ flag){
  if (*flag != DT) return;
  __shared__ float sh[512];
  __shared__ float mS[4], sS[4];
  for (int b = 0; b < 4; b++){
    sh[threadIdx.x]     = partials[(b*256+threadIdx.x)*2];
    sh[256+threadIdx.x] = partials[(b*256+threadIdx.x)*2+1];
    __syncthreads();
    for (int st = 128; st > 0; st >>= 1){
      if (threadIdx.x < st){
        sh[threadIdx.x]     += sh[threadIdx.x + st];
        sh[256+threadIdx.x] += sh[256+threadIdx.x + st];
      }
      __syncthreads();
    }
    if (threadIdx.x == 0){
      float mean = sh[0] / (float)PER_B;
      float var  = sh[256] / (float)PER_B - mean*mean;
      float stdv = sqrtf(var + EPS_F);
      mS[b] = mean; sS[b] = stdv;
      stats[b] = mean; stats[4+b] = stdv;
    }
    __syncthreads();
  }
  for (int t = threadIdx.x; t < 384; t += 256){
    int b = t / 96, c = t % 96;
    stats[8+t]   = sS[b]*rdf<DT>(m1w,c) + rdf<DT>(m1b,c);
    stats[392+t] = mS[b]*rdf<DT>(m2w,c) + rdf<DT>(m2b,c);
  }
}

// ---------- K3: rel-pos bias table, transposed [h][m][n] ----------
template<int DT>
__global__ __launch_bounds__(256) void k_bias(const void* w1, const void* b1v,
    const void* w2, const void* b2v, float* __restrict__ biasT, const int* __restrict__ flag){
  if (*flag != DT) return;
  int i = blockIdx.x >> 6, j = blockIdx.x & 63;   // i = query n, j = key m
  int dy = (i>>3) - (j>>3), dx = (i&7) - (j&7);
  float fy = (float)dy, fx = (float)dx;
  float r0 = copysignf(log1pf(fabsf(fy)), fy);
  float r1 = copysignf(log1pf(fabsf(fx)), fx);
  int t = threadIdx.x;
  float hb = fmaxf(r0*rdf<DT>(w1,t*2) + r1*rdf<DT>(w1,t*2+1) + rdf<DT>(b1v,t), 0.f);
  __shared__ float sh[256];
  for (int h = 0; h < 3; h++){
    sh[t] = hb * rdf<DT>(w2, h*256+t);
    __syncthreads();
    for (int st = 128; st > 0; st >>= 1){ if (t < st) sh[t] += sh[t+st]; __syncthreads(); }
    if (t == 0) biasT[h*4096 + j*64 + i] = sh[0] + rdf<DT>(b2v, h);
    __syncthreads();
  }
}

// ---------- K4: fused AGN: x -> xn2 (bf16) ----------
template<int DT>
__global__ __launch_bounds__(256) void k_agn_fused(const void* __restrict__ x,
    const float* __restrict__ stats,
    const void* la1w, const void* la1b, const void* la2w, const void* la2b,
    const void* ta1w, const void* ta1b, const void* ta2w, const void* ta2b,
    const void* agnw, const void* agnb,
    bf16* __restrict__ xn2, const int* __restrict__ flag){
  if (*flag != DT) return;
  __shared__ float xs[400];   // 20x20 zero-padded
  __shared__ float ts[324];   // 18x18
  __shared__ float us[324];
  int idx = blockIdx.x;
  int tile = idx & 255; int bc = idx >> 8; int c = bc % 96; int b = bc / 96;
  int oy = (tile >> 4) << 4, ox = (tile & 15) << 4;
  float mean = stats[b], sd = stats[4+b];
  size_t xbase = ((size_t)bc) << 16;
  for (int it = threadIdx.x; it < 400; it += 256){
    int ly = it / 20, lx = it % 20;
    int gy = oy - 2 + ly, gx = ox - 2 + lx;
    float v = 0.f;
    if (gy >= 0 && gy < 256 && gx >= 0 && gx < 256)
      v = (rdf<DT>(x, xbase + (gy<<8) + gx) - mean) / sd;
    xs[it] = v;
  }
  float wl1[9], wt1[9], wl2[9], wt2[9];
  #pragma unroll
  for (int k = 0; k < 9; k++){
    wl1[k] = rdf<DT>(la1w, c*9+k); wt1[k] = rdf<DT>(ta1w, c*9+k);
    wl2[k] = rdf<DT>(la2w, c*9+k); wt2[k] = rdf<DT>(ta2w, c*9+k);
  }
  float bl1 = rdf<DT>(la1b, c), bt1 = rdf<DT>(ta1b, c);
  __syncthreads();
  for (int it = threadIdx.x; it < 324; it += 256){
    int ly = it / 18, lx = it % 18;
    int cy = oy - 1 + ly, cx = ox - 1 + lx;
    float a1 = 0.f, a2 = 0.f;
    if (cy >= 0 && cy < 256 && cx >= 0 && cx < 256){
      a1 = bl1; a2 = bt1;
      #pragma unroll
      for (int dy = 0; dy < 3; dy++)
        #pragma unroll
        for (int dx = 0; dx < 3; dx++){
          float v = xs[(ly+dy)*20 + lx+dx];
          a1 += v * wl1[dy*3+dx]; a2 += v * wt1[dy*3+dx];
        }
      a1 = fmaxf(a1, 0.f); a2 = fmaxf(a2, 0.f);
    }
    ts[it] = a1; us[it] = a2;
  }
  __syncthreads();
  int ty = threadIdx.x >> 4, tx0 = threadIdx.x & 15;
  float l = rdf<DT>(la2b, c), t = rdf<DT>(ta2b, c);
  #pragma unroll
  for (int dy = 0; dy < 3; dy++)
    #pragma unroll
    for (int dx = 0; dx < 3; dx++){
      l += ts[(ty+dy)*18 + tx0+dx] * wl2[dy*3+dx];
      t += us[(ty+dy)*18 + tx0+dx] * wt2[dy*3+dx];
    }
  float v = xs[(ty+2)*20 + tx0+2];
  float r = v*(rdf<DT>(agnw,c)*stats[8+bc]) + (rdf<DT>(agnb,c) + stats[392+bc]) + l + t;
  xn2[xbase + ((oy+ty)<<8) + ox + tx0] = f2b(r);
}

// ---------- K5: MFMA mega window kernel ----------
// LDS arena 62208 B, overlaid regions (all phase-transitions barrier-separated):
//  XS  @0      short[144][104] = 29952  (P1-P2)  halo, pixel-major [t][c]
//  KT  @0      short[64][104]  = 13312  (P3-P4)  K, pixel-major [m][d], pre-scaled
//  VD  @13312  short[96][72]   = 13824  (P3-P4)  V, d-major [d][m]
//  OS  @0      short[64][104]  = 13312  (P5)     attn out, pixel-major [n][d]
//  QB  @29952  short[16][148] x4 waves = 18944 (P2)  per-wave Q scratch [c_loc][t]
//  XC  @29952  short[64][104]  = 13312  (P3)     center pixels [n][c]
//  PS  @29952  short[16][72] x4 waves  =  9216 (P4)  per-wave P scratch [n_loc][m]
//  CS  @48896  short[64][104]  = 13312  (P2-P4)  conv-q, pixel-major [n][c]
#define XS_OFF 0
#define KT_OFF 0
#define VD_OFF 13312
#define OS_OFF 0
#define QB_OFF 29952
#define XC_OFF 29952
#define PS_OFF 29952
#define CS_OFF 48896

template<int DT>
__global__ __launch_bounds__(256) void k_attn_mega(const bf16* __restrict__ xn2,
    const void* qw, const void* qb, const void* kvw, const void* kvb,
    const void* dww, const void* dwb, const void* pw, const void* pb,
    const void* lsin, const float* __restrict__ biasT,
    const void* __restrict__ xin, const float* __restrict__ stats,
    void* __restrict__ outp, const int* __restrict__ flag){
  if (*flag != DT) return;
  __shared__ __align__(16) char smem[62208];
  int tid = threadIdx.x, wid = blockIdx.x;
  int b = wid >> 10, wy = (wid >> 5) & 31, wx = wid & 31;
  int wv = tid >> 6, ln = tid & 63;
  int r = ln & 15, q = ln >> 4;

  // ---- P1: stage reflected 12x12 halo, pixel-major xs[t][c]
  {
    short* xs = (short*)(smem + XS_OFF);
    for (int it = tid; it < 13824; it += 256){
      int t = it % 144, c = it / 144;
      int ty = (wy<<3) - 2 + t/12, tx = (wx<<3) - 2 + t%12;
      ty = ty < 0 ? -ty : (ty > 255 ? 510 - ty : ty);
      tx = tx < 0 ? -tx : (tx > 255 ? 510 - tx : tx);
      xs[t*104 + c] = ((const short*)xn2)[(((size_t)(b*96 + c))<<16) + (ty<<8) + tx];
    }
  }
  __syncthreads();

  // ---- P2: Q GEMM (M=96,N=144,K=96) per-wave mt tiles + immediate 5x5 dwconv
  {
    const short* xs = (const short*)(smem + XS_OFF);
    short* Qb = (short*)(smem + QB_OFF) + wv*2368;   // [16][148] shorts
    short* cs = (short*)(smem + CS_OFF);
    int ty0 = (ln>>3)+2, tx0 = (ln&7)+2;
    for (int mt = wv; mt < 6; mt += 4){
      short8v aw[3];
      #pragma unroll
      for (int kt = 0; kt < 3; kt++)
        aw[kt] = ld8<DT>(qw, (size_t)(16*mt + r)*96 + 32*kt + 8*q);
      float qb4[4];
      #pragma unroll
      for (int j = 0; j < 4; j++) qb4[j] = rdf<DT>(qb, 16*mt + 4*q + j);
      for (int nt = 0; nt < 9; nt++){
        f32x4 acc = {0.f,0.f,0.f,0.f};
        #pragma unroll
        for (int kt = 0; kt < 3; kt++){
          short8v bx = *(const short8v*)(xs + (16*nt + r)*104 + 32*kt + 8*q);
          acc = __builtin_amdgcn_mfma_f32_16x16x32_bf16(aw[kt], bx, acc, 0, 0, 0);
        }
        #pragma unroll
        for (int j = 0; j < 4; j++)
          Qb[(4*q+j)*148 + 16*nt + r] = f2bs(acc[j] + qb4[j]);
      }
      asm volatile("s_waitcnt lgkmcnt(0)" ::: "memory");
      for (int cl = 0; cl < 16; cl++){
        int c = 16*mt + cl;
        float a = rdf<DT>(dwb, c);
        #pragma unroll
        for (int dy = -2; dy <= 2; dy++)
          #pragma unroll
          for (int dx = -2; dx <= 2; dx++)
            a += bs2f(Qb[cl*148 + (ty0+dy)*12 + tx0+dx]) * rdf<DT>(dww, c*25 + (dy+2)*5 + dx+2);
        cs[ln*104 + c] = f2bs(a);
      }
      asm volatile("s_waitcnt lgkmcnt(0)" ::: "memory");
    }
  }
  __syncthreads();

  // ---- P3: re-stage centers xc[n][c], then KV GEMM (M=192,N=64,K=96)
  {
    short* xc = (short*)(smem + XC_OFF);
    for (int it = tid; it < 768; it += 256){
      int c = it >> 3, row = it & 7;
      const short* src = (const short*)xn2 + (((size_t)(b*96 + c))<<16)
                         + (((wy<<3)+row)<<8) + (wx<<3);
      short8v v = *(const short8v*)src;
      #pragma unroll
      for (int px = 0; px < 8; px++) xc[(row*8+px)*104 + c] = v[px];
    }
  }
  __syncthreads();
  {
    const short* xc = (const short*)(smem + XC_OFF);
    short* Kt = (short*)(smem + KT_OFF);
    short* Vd = (short*)(smem + VD_OFF);
    for (int mtk = wv; mtk < 12; mtk += 4){
      short8v aw[3];
      #pragma unroll
      for (int kt = 0; kt < 3; kt++)
        aw[kt] = ld8<DT>(kvw, (size_t)(16*mtk + r)*96 + 32*kt + 8*q);
      float bb[4];
      #pragma unroll
      for (int j = 0; j < 4; j++) bb[j] = rdf<DT>(kvb, 16*mtk + 4*q + j);
      for (int nt = 0; nt < 4; nt++){
        f32x4 acc = {0.f,0.f,0.f,0.f};
        #pragma unroll
        for (int kt = 0; kt < 3; kt++){
          short8v bx = *(const short8v*)(xc + (16*nt + r)*104 + 32*kt + 8*q);
          acc = __builtin_amdgcn_mfma_f32_16x16x32_bf16(aw[kt], bx, acc, 0, 0, 0);
        }
        if (mtk < 6){
          short4v kv;
          #pragma unroll
          for (int j = 0; j < 4; j++) kv[j] = f2bs((acc[j] + bb[j]) * SCALE_F);
          *(short4v*)(Kt + (16*nt + r)*104 + 16*mtk + 4*q) = kv;
        } else {
          #pragma unroll
          for (int j = 0; j < 4; j++)
            Vd[(16*(mtk-6) + 4*q + j)*72 + 16*nt + r] = f2bs(acc[j] + bb[j]);
        }
      }
    }
  }
  __syncthreads();

  // ---- P4: attention. Wave wv owns n-tile nt=wv for all 3 heads.
  float o_save[24];
  {
    const short* cs = (const short*)(smem + CS_OFF);
    const short* Kt = (const short*)(smem + KT_OFF);
    const short* Vd = (const short*)(smem + VD_OFF);
    short* Psw = (short*)(smem + PS_OFF) + wv*1152;   // [16][72]
    float lsv = __expf(fminf(rdf<DT>(lsin, 0), LOGIT_MAX_F));
    #pragma unroll
    for (int h = 0; h < 3; h++){
      short8v qa = *(const short8v*)(cs + (16*wv + r)*104 + 32*h + 8*q);
      f32x4 s[4];
      #pragma unroll
      for (int mt = 0; mt < 4; mt++){
        short8v kb = *(const short8v*)(Kt + (16*mt + r)*104 + 32*h + 8*q);
        f32x4 z = {0.f,0.f,0.f,0.f};
        s[mt] = __builtin_amdgcn_mfma_f32_16x16x32_bf16(qa, kb, z, 0, 0, 0);
      }
      float l[4][4];
      #pragma unroll
      for (int mt = 0; mt < 4; mt++){
        float4 bv = *(const float4*)(biasT + h*4096 + (16*mt + r)*64 + 16*wv + 4*q);
        l[mt][0] = s[mt][0]*lsv + bv.x;
        l[mt][1] = s[mt][1]*lsv + bv.y;
        l[mt][2] = s[mt][2]*lsv + bv.z;
        l[mt][3] = s[mt][3]*lsv + bv.w;
      }
      float mx[4], sm[4];
      #pragma unroll
      for (int j = 0; j < 4; j++){
        float m0 = fmaxf(fmaxf(l[0][j], l[1][j]), fmaxf(l[2][j], l[3][j]));
        m0 = fmaxf(m0, __shfl_xor(m0, 1));
        m0 = fmaxf(m0, __shfl_xor(m0, 2));
        m0 = fmaxf(m0, __shfl_xor(m0, 4));
        m0 = fmaxf(m0, __shfl_xor(m0, 8));
        mx[j] = m0; sm[j] = 0.f;
      }
      #pragma unroll
      for (int mt = 0; mt < 4; mt++)
        #pragma unroll
        for (int j = 0; j < 4; j++){
          float p = __expf(l[mt][j] - mx[j]);
          sm[j] += p;
          Psw[(4*q+j)*72 + 16*mt + r] = f2bs(p);
        }
      #pragma unroll
      for (int j = 0; j < 4; j++){
        sm[j] += __shfl_xor(sm[j], 1);
        sm[j] += __shfl_xor(sm[j], 2);
        sm[j] += __shfl_xor(sm[j], 4);
        sm[j] += __shfl_xor(sm[j], 8);
      }
      float inv[4];
      #pragma unroll
      for (int j = 0; j < 4; j++) inv[j] = 1.f / sm[j];
      asm volatile("s_waitcnt lgkmcnt(0)" ::: "memory");
      short8v pa0 = *(const short8v*)(Psw + r*72 + 8*q);
      short8v pa1 = *(const short8v*)(Psw + r*72 + 32 + 8*q);
      #pragma unroll
      for (int dt = 0; dt < 2; dt++){
        f32x4 o = {0.f,0.f,0.f,0.f};
        short8v vb0 = *(const short8v*)(Vd + (32*h + 16*dt + r)*72 + 8*q);
        short8v vb1 = *(const short8v*)(Vd + (32*h + 16*dt + r)*72 + 32 + 8*q);
        o = __builtin_amdgcn_mfma_f32_16x16x32_bf16(pa0, vb0, o, 0, 0, 0);
        o = __builtin_amdgcn_mfma_f32_16x16x32_bf16(pa1, vb1, o, 0, 0, 0);
        #pragma unroll
        for (int j = 0; j < 4; j++) o_save[h*8 + dt*4 + j] = o[j] * inv[j];
      }
      asm volatile("s_waitcnt lgkmcnt(0)" ::: "memory");
    }
  }
  __syncthreads();

  // ---- write osT[n][d] over Kt region
  {
    short* os = (short*)(smem + OS_OFF);
    #pragma unroll
    for (int h = 0; h < 3; h++)
      #pragma unroll
      for (int dt = 0; dt < 2; dt++)
        #pragma unroll
        for (int j = 0; j < 4; j++)
          os[(16*wv + 4*q + j)*104 + 32*h + 16*dt + r] = f2bs(o_save[h*8 + dt*4 + j]);
  }
  __syncthreads();

  // ---- P5: proj GEMM (M=96,N=64,K=96) + residual epilogue
  {
    const short* os = (const short*)(smem + OS_OFF);
    short8v ob[3];
    #pragma unroll
    for (int kt = 0; kt < 3; kt++)
      ob[kt] = *(const short8v*)(os + (16*wv + r)*104 + 32*kt + 8*q);
    for (int mt = 0; mt < 6; mt++){
      f32x4 acc = {0.f,0.f,0.f,0.f};
      #pragma unroll
      for (int kt = 0; kt < 3; kt++){
        short8v aw = ld8<DT>(pw, (size_t)(16*mt + r)*96 + 32*kt + 8*q);
        acc = __builtin_amdgcn_mfma_f32_16x16x32_bf16(aw, ob[kt], acc, 0, 0, 0);
      }
      #pragma unroll
      for (int j = 0; j < 4; j++){
        int oc = 16*mt + 4*q + j;
        int n  = 16*wv + r;
        int gy = (wy<<3) + (n>>3), gx = (wx<<3) + (n&7);
        size_t gi = (((size_t)(b*96 + oc))<<16) + (gy<<8) + gx;
        float a = acc[j] + rdf<DT>(pb, oc);
        float x1 = rdf<DT>(xin, gi) + a*stats[8 + b*96 + oc] + stats[392 + b*96 + oc];
        wrf<DT>(outp, gi, x1);
      }
    }
  }
}

// ---------- K6: MFMA MLP in-place on d_out ----------
template<int DT>
__global__ __launch_bounds__(256) void k_mlp_mfma(void* __restrict__ io,
    const void* w1, const void* b1, const void* w2, const void* b2v,
    const int* __restrict__ flag){
  if (*flag != DT) return;
  __shared__ short x1s[64*104];   // [pixel][channel], pad 96->104
  int blk = blockIdx.x; int b = blk >> 10; int pix0 = (blk & 1023) << 6;
  int tid = threadIdx.x;
  for (int it = tid; it < 6144; it += 256){
    int c = it >> 6, p = it & 63;
    size_t gi = (((size_t)(b*96 + c))<<16) + pix0 + p;
    short v = DT ? f2bs(((const float*)io)[gi]) : ((const short*)io)[gi];
    x1s[p*104 + c] = v;
  }
  __syncthreads();

  int w = tid >> 6, l = tid & 63;
  int r = l & 15, q = l >> 4;
  int pw = w << 4;

  short8v B1[3];
  #pragma unroll
  for (int kt = 0; kt < 3; kt++)
    B1[kt] = *(const short8v*)&x1s[(pw + r)*104 + 32*kt + 8*q];

  short8v B2[12];
  #pragma unroll
  for (int t = 0; t < 12; t++){
    f32x4 accA = {0.f,0.f,0.f,0.f};
    f32x4 accB = {0.f,0.f,0.f,0.f};
    #pragma unroll
    for (int kt = 0; kt < 3; kt++){
      short8v aA = ld8<DT>(w1, (size_t)(32*t + r)*96      + 32*kt + 8*q);
      short8v aB = ld8<DT>(w1, (size_t)(32*t + 16 + r)*96 + 32*kt + 8*q);
      accA = __builtin_amdgcn_mfma_f32_16x16x32_bf16(aA, B1[kt], accA, 0, 0, 0);
      accB = __builtin_amdgcn_mfma_f32_16x16x32_bf16(aB, B1[kt], accB, 0, 0, 0);
    }
    short8v h;
    #pragma unroll
    for (int j = 0; j < 4; j++){
      float hA = accA[j] + rdf<DT>(b1, 32*t + 4*q + j);
      float hB = accB[j] + rdf<DT>(b1, 32*t + 16 + 4*q + j);
      h[j]   = f2bs(fmaxf(hA, 0.f));
      h[4+j] = f2bs(fmaxf(hB, 0.f));
    }
    B2[t] = h;
  }

  for (int mt = 0; mt < 6; mt++){
    f32x4 acc = {0.f,0.f,0.f,0.f};
    #pragma unroll
    for (int t = 0; t < 12; t++){
      short8v a = ld4x2<DT>(w2, (size_t)(16*mt + r)*384 + 32*t + 4*q);
      acc = __builtin_amdgcn_mfma_f32_16x16x32_bf16(a, B2[t], acc, 0, 0, 0);
    }
    #pragma unroll
    for (int j = 0; j < 4; j++){
      int oc = 16*mt + 4*q + j;
      size_t gi = (((size_t)(b*96 + oc))<<16) + pix0 + pw + r;
      wrf<DT>(io, gi, rdf<DT>(io, gi) + acc[j] + rdf<DT>(b2v, oc));
    }
  }
}

extern "C" void kernel_launch(void* const* d_in, const int* in_sizes, int n_in,
                              void* d_out, int out_size, void* d_ws, size_t ws_size,
                              hipStream_t stream) {
  const void* x      = d_in[0];
  const void* agnw   = d_in[1];
  const void* agnb   = d_in[2];
  const void* meta1w = d_in[3];
  const void* meta1b = d_in[4];
  const void* meta2w = d_in[5];
  const void* meta2b = d_in[6];
  const void* la1w   = d_in[7];
  const void* la1b   = d_in[8];
  const void* la2w   = d_in[9];
  const void* la2b   = d_in[10];
  const void* ta1w   = d_in[11];
  const void* ta1b   = d_in[12];
  const void* ta2w   = d_in[13];
  const void* ta2b   = d_in[14];
  const void* qw     = d_in[15];
  const void* qb     = d_in[16];
  const void* kvw    = d_in[17];
  const void* kvb    = d_in[18];
  const void* dww    = d_in[19];
  const void* dwb    = d_in[20];
  const void* pw     = d_in[21];
  const void* pb     = d_in[22];
  const void* lsin   = d_in[23];
  const void* rpw1   = d_in[24];
  const void* rpb1   = d_in[25];
  const void* rpw2   = d_in[26];
  const void* rpb2   = d_in[27];
  const void* m1w    = d_in[28];
  const void* m1b    = d_in[29];
  const void* m2w    = d_in[30];
  const void* m2b    = d_in[31];

  // ws: flag @0 | partials @256 | stats @8448 | biasT @12288 | xn2 @65536 (48MB)
  char* ws = (char*)d_ws;
  int*   flag     = (int*)ws;
  float* partials = (float*)(ws + 256);
  float* stats    = (float*)(ws + 8448);
  float* biasT    = (float*)(ws + 12288);
  bf16*  xn2      = (bf16*)(ws + 65536);

  k_detect<<<1, 256, 0, stream>>>(x, flag);

  // bf16 variant
  k_stats_partial<0><<<1024, 256, 0, stream>>>(x, partials, flag);
  k_stats_final<0>  <<<1,    256, 0, stream>>>(partials, meta1w, meta1b, meta2w, meta2b, stats, flag);
  k_bias<0>         <<<4096, 256, 0, stream>>>(rpw1, rpb1, rpw2, rpb2, biasT, flag);
  k_agn_fused<0>    <<<98304,256, 0, stream>>>(x, stats, la1w, la1b, la2w, la2b,
                                               ta1w, ta1b, ta2w, ta2b, agnw, agnb, xn2, flag);
  k_attn_mega<0>    <<<4096, 256, 0, stream>>>(xn2, qw, qb, kvw, kvb, dww, dwb, pw, pb,
                                               lsin, biasT, x, stats, d_out, flag);
  k_mlp_mfma<0>     <<<4096, 256, 0, stream>>>(d_out, m1w, m1b, m2w, m2b, flag);

  // fp32 variant
  k_stats_partial<1><<<1024, 256, 0, stream>>>(x, partials, flag);
  k_stats_final<1>  <<<1,    256, 0, stream>>>(partials, meta1w, meta1b, meta2w, meta2b, stats, flag);
  k_bias<1>         <<<4096, 256, 0, stream>>>(rpw1, rpb1, rpw2, rpb2, biasT, flag);
  k_agn_fused<1>    <<<98304,256, 0, stream>>>(x, stats, la1w, la1b, la2w, la2b,
                                               ta1w, ta1b, ta2w, ta2b, agnw, agnb, xn2, flag);
  k_attn_mega<1>    <<<4096, 256, 0, stream>>>(xn2, qw, qb, kvw, kvb, dww, dwb, pw, pb,
                                               lsin, biasT, x, stats, d_out, flag);
  k_mlp_mfma<1>     <<<4096, 256, 0, stream>>>(d_out, m1w, m1b, m2w, m2b, flag);
}

// Round 3
// 1138.924 us; speedup vs baseline: 2.8539x; 1.2641x over previous
//
#include <hip/hip_runtime.h>
#include <hip/hip_bf16.h>

typedef __hip_bfloat16 bf16;

#define PER_B     6291456            // 96*65536
#define EPS_F     1e-5f
#define SCALE_F   0.17677669529663687f   // 32^-0.5
#define LOGIT_MAX_F 4.605170185988092f   // log(100)

__device__ __forceinline__ float b2f(bf16 v){ return __bfloat162float(v); }
__device__ __forceinline__ bf16  f2b(float v){ return __float2bfloat16(v); }

// DT=0: buffers are bf16.  DT=1: buffers are fp32.
template<int DT> __device__ __forceinline__ float rdf(const void* p, size_t i){
  return DT ? ((const float*)p)[i] : b2f(((const bf16*)p)[i]);
}
template<int DT> __device__ __forceinline__ void wrf(void* p, size_t i, float v){
  if (DT) ((float*)p)[i] = v; else ((bf16*)p)[i] = f2b(v);
}
// paired weight load (i must be even)
template<int DT> __device__ __forceinline__ float2 rd2(const void* p, size_t i){
  if (DT) return *(const float2*)((const float*)p + i);
  unsigned u = *(const unsigned*)((const bf16*)p + i);
  return make_float2(__uint_as_float(u << 16), __uint_as_float(u & 0xffff0000u));
}

// ---------- MFMA helpers ----------
typedef __attribute__((ext_vector_type(8))) short short8v;   // 8 bf16 (4 VGPRs)
typedef __attribute__((ext_vector_type(4))) short short4v;
typedef __attribute__((ext_vector_type(4))) float f32x4;

// fp32 -> bf16 bits, round-to-nearest-even (finite inputs)
__device__ __forceinline__ short f2bs(float v){
  unsigned u = __float_as_uint(v);
  return (short)((u + 0x7fffu + ((u >> 16) & 1u)) >> 16);
}
__device__ __forceinline__ float bs2f(short s){
  return __uint_as_float(((unsigned)(unsigned short)s) << 16);
}

// load 8 contiguous weights (elements i..i+8) as bf16 bits; i % 8 == 0
template<int DT> __device__ __forceinline__ short8v ld8(const void* p, size_t i){
  short8v a;
  if (DT){
    const float* f = (const float*)p + i;
    float4 lo = *(const float4*)f;
    float4 hi = *(const float4*)(f + 4);
    a[0]=f2bs(lo.x); a[1]=f2bs(lo.y); a[2]=f2bs(lo.z); a[3]=f2bs(lo.w);
    a[4]=f2bs(hi.x); a[5]=f2bs(hi.y); a[6]=f2bs(hi.z); a[7]=f2bs(hi.w);
  } else {
    a = *(const short8v*)((const short*)p + i);
  }
  return a;
}
// load two 4-element chunks at i0 and i0+16 (elements); i0 % 4 == 0
template<int DT> __device__ __forceinline__ short8v ld4x2(const void* p, size_t i0){
  short8v a;
  if (DT){
    const float* f = (const float*)p;
    float4 lo = *(const float4*)(f + i0);
    float4 hi = *(const float4*)(f + i0 + 16);
    a[0]=f2bs(lo.x); a[1]=f2bs(lo.y); a[2]=f2bs(lo.z); a[3]=f2bs(lo.w);
    a[4]=f2bs(hi.x); a[5]=f2bs(hi.y); a[6]=f2bs(hi.z); a[7]=f2bs(hi.w);
  } else {
    const short* s = (const short*)p;
    short4v lo = *(const short4v*)(s + i0);
    short4v hi = *(const short4v*)(s + i0 + 16);
    a[0]=lo[0]; a[1]=lo[1]; a[2]=lo[2]; a[3]=lo[3];
    a[4]=hi[0]; a[5]=hi[1]; a[6]=hi[2]; a[7]=hi[3];
  }
  return a;
}

// ---------- K0: dtype detector ----------
__global__ __launch_bounds__(256) void k_detect(const void* __restrict__ x, int* __restrict__ flag){
  __shared__ int cnt;
  if (threadIdx.x == 0) cnt = 0;
  __syncthreads();
  float v = b2f(((const bf16*)x)[(size_t)threadIdx.x * 16]);
  int bad = (!(v == v)) || (fabsf(v) > 1e20f);
  if (bad) atomicAdd(&cnt, 1);
  __syncthreads();
  if (threadIdx.x == 0) *flag = (cnt >= 4) ? 1 : 0;
}

// ---------- K1: per-batch partial sums ----------
template<int DT>
__global__ __launch_bounds__(256) void k_stats_partial(const void* __restrict__ x,
    float* __restrict__ partials, const int* __restrict__ flag){
  if (*flag != DT) return;
  int blk = blockIdx.x;
  int b = blk >> 8, chunk = blk & 255;
  const int chunkN = PER_B / 256;
  size_t base = (size_t)b * PER_B + (size_t)chunk * chunkN;
  float s = 0.f, ss = 0.f;
  for (int i = threadIdx.x; i < chunkN; i += 256){
    float v = rdf<DT>(x, base + i); s += v; ss += v*v;
  }
  __shared__ float sh[512];
  sh[threadIdx.x] = s; sh[256 + threadIdx.x] = ss;
  __syncthreads();
  for (int st = 128; st > 0; st >>= 1){
    if (threadIdx.x < st){
      sh[threadIdx.x]     += sh[threadIdx.x + st];
      sh[256+threadIdx.x] += sh[256+threadIdx.x + st];
    }
    __syncthreads();
  }
  if (threadIdx.x == 0){ partials[blk*2] = sh[0]; partials[blk*2+1] = sh[256]; }
}

// ---------- K2: finalize mean/std + rescale/rebias ----------
template<int DT>
__global__ __launch_bounds__(256) void k_stats_final(const float* __restrict__ partials,
    const void* m1w, const void* m1b, const void* m2w, const void* m2b,
    float* __restrict__ stats, const int* __restrict__ flag){
  if (*flag != DT) return;
  __shared__ float sh[512];
  __shared__ float mS[4], sS[4];
  for (int b = 0; b < 4; b++){
    sh[threadIdx.x]     = partials[(b*256+threadIdx.x)*2];
    sh[256+threadIdx.x] = partials[(b*256+threadIdx.x)*2+1];
    __syncthreads();
    for (int st = 128; st > 0; st >>= 1){
      if (threadIdx.x < st){
        sh[threadIdx.x]     += sh[threadIdx.x + st];
        sh[256+threadIdx.x] += sh[256+threadIdx.x + st];
      }
      __syncthreads();
    }
    if (threadIdx.x == 0){
      float mean = sh[0] / (float)PER_B;
      float var  = sh[256] / (float)PER_B - mean*mean;
      float stdv = sqrtf(var + EPS_F);
      mS[b] = mean; sS[b] = stdv;
      stats[b] = mean; stats[4+b] = stdv;
    }
    __syncthreads();
  }
  for (int t = threadIdx.x; t < 384; t += 256){
    int b = t / 96, c = t % 96;
    stats[8+t]   = sS[b]*rdf<DT>(m1w,c) + rdf<DT>(m1b,c);
    stats[392+t] = mS[b]*rdf<DT>(m2w,c) + rdf<DT>(m2b,c);
  }
}

// ---------- K3: rel-pos bias table, transposed [h][m][n] ----------
template<int DT>
__global__ __launch_bounds__(256) void k_bias(const void* w1, const void* b1v,
    const void* w2, const void* b2v, float* __restrict__ biasT, const int* __restrict__ flag){
  if (*flag != DT) return;
  int i = blockIdx.x >> 6, j = blockIdx.x & 63;   // i = query n, j = key m
  int dy = (i>>3) - (j>>3), dx = (i&7) - (j&7);
  float fy = (float)dy, fx = (float)dx;
  float r0 = copysignf(log1pf(fabsf(fy)), fy);
  float r1 = copysignf(log1pf(fabsf(fx)), fx);
  int t = threadIdx.x;
  float hb = fmaxf(r0*rdf<DT>(w1,t*2) + r1*rdf<DT>(w1,t*2+1) + rdf<DT>(b1v,t), 0.f);
  __shared__ float sh[256];
  for (int h = 0; h < 3; h++){
    sh[t] = hb * rdf<DT>(w2, h*256+t);
    __syncthreads();
    for (int st = 128; st > 0; st >>= 1){ if (t < st) sh[t] += sh[t+st]; __syncthreads(); }
    if (t == 0) biasT[h*4096 + j*64 + i] = sh[0] + rdf<DT>(b2v, h);
    __syncthreads();
  }
}

// ---------- K4: fused AGN: x -> xn2 (bf16) ----------
template<int DT>
__global__ __launch_bounds__(256) void k_agn_fused(const void* __restrict__ x,
    const float* __restrict__ stats,
    const void* la1w, const void* la1b, const void* la2w, const void* la2b,
    const void* ta1w, const void* ta1b, const void* ta2w, const void* ta2b,
    const void* agnw, const void* agnb,
    bf16* __restrict__ xn2, const int* __restrict__ flag){
  if (*flag != DT) return;
  __shared__ float xs[400];   // 20x20 zero-padded
  __shared__ float ts[324];   // 18x18
  __shared__ float us[324];
  int idx = blockIdx.x;
  int tile = idx & 255; int bc = idx >> 8; int c = bc % 96; int b = bc / 96;
  int oy = (tile >> 4) << 4, ox = (tile & 15) << 4;
  float mean = stats[b], sd = stats[4+b];
  size_t xbase = ((size_t)bc) << 16;
  for (int it = threadIdx.x; it < 400; it += 256){
    int ly = it / 20, lx = it % 20;
    int gy = oy - 2 + ly, gx = ox - 2 + lx;
    float v = 0.f;
    if (gy >= 0 && gy < 256 && gx >= 0 && gx < 256)
      v = (rdf<DT>(x, xbase + (gy<<8) + gx) - mean) / sd;
    xs[it] = v;
  }
  float wl1[9], wt1[9], wl2[9], wt2[9];
  #pragma unroll
  for (int k = 0; k < 9; k++){
    wl1[k] = rdf<DT>(la1w, c*9+k); wt1[k] = rdf<DT>(ta1w, c*9+k);
    wl2[k] = rdf<DT>(la2w, c*9+k); wt2[k] = rdf<DT>(ta2w, c*9+k);
  }
  float bl1 = rdf<DT>(la1b, c), bt1 = rdf<DT>(ta1b, c);
  __syncthreads();
  for (int it = threadIdx.x; it < 324; it += 256){
    int ly = it / 18, lx = it % 18;
    int cy = oy - 1 + ly, cx = ox - 1 + lx;
    float a1 = 0.f, a2 = 0.f;
    if (cy >= 0 && cy < 256 && cx >= 0 && cx < 256){
      a1 = bl1; a2 = bt1;
      #pragma unroll
      for (int dy = 0; dy < 3; dy++)
        #pragma unroll
        for (int dx = 0; dx < 3; dx++){
          float v = xs[(ly+dy)*20 + lx+dx];
          a1 += v * wl1[dy*3+dx]; a2 += v * wt1[dy*3+dx];
        }
      a1 = fmaxf(a1, 0.f); a2 = fmaxf(a2, 0.f);
    }
    ts[it] = a1; us[it] = a2;
  }
  __syncthreads();
  int ty = threadIdx.x >> 4, tx0 = threadIdx.x & 15;
  float l = rdf<DT>(la2b, c), t = rdf<DT>(ta2b, c);
  #pragma unroll
  for (int dy = 0; dy < 3; dy++)
    #pragma unroll
    for (int dx = 0; dx < 3; dx++){
      l += ts[(ty+dy)*18 + tx0+dx] * wl2[dy*3+dx];
      t += us[(ty+dy)*18 + tx0+dx] * wt2[dy*3+dx];
    }
  float v = xs[(ty+2)*20 + tx0+2];
  float r = v*(rdf<DT>(agnw,c)*stats[8+bc]) + (rdf<DT>(agnb,c) + stats[392+bc]) + l + t;
  xn2[xbase + ((oy+ty)<<8) + ox + tx0] = f2b(r);
}

// ---------- K5: MFMA mega window kernel ----------
// LDS arena 62208 B, overlaid regions (all phase-transitions barrier-separated):
//  XS  @0      short[144][104] = 29952  (P1-P2)  halo, pixel-major [t][c]
//  KT  @0      short[64][104]  = 13312  (P3-P4)  K, pixel-major [m][d], pre-scaled
//  VD  @13312  short[96][72]   = 13824  (P3-P4)  V, d-major [d][m]
//  OS  @0      short[64][104]  = 13312  (P5)     attn out, pixel-major [n][d]
//  QB  @29952  short[16][148] x4 waves = 18944 (P2)  per-wave Q scratch [c_loc][t]
//  XC  @29952  short[64][104]  = 13312  (P3)     center pixels [n][c]
//  PS  @29952  short[16][72] x4 waves  =  9216 (P4)  per-wave P scratch [n_loc][m]
//  CS  @48896  short[64][104]  = 13312  (P2-P4)  conv-q, pixel-major [n][c]
#define XS_OFF 0
#define KT_OFF 0
#define VD_OFF 13312
#define OS_OFF 0
#define QB_OFF 29952
#define XC_OFF 29952
#define PS_OFF 29952
#define CS_OFF 48896

template<int DT>
__global__ __launch_bounds__(256) void k_attn_mega(const bf16* __restrict__ xn2,
    const void* qw, const void* qb, const void* kvw, const void* kvb,
    const void* dww, const void* dwb, const void* pw, const void* pb,
    const void* lsin, const float* __restrict__ biasT,
    const void* __restrict__ xin, const float* __restrict__ stats,
    void* __restrict__ outp, const int* __restrict__ flag){
  if (*flag != DT) return;
  __shared__ __align__(16) char smem[62208];
  int tid = threadIdx.x, wid = blockIdx.x;
  int b = wid >> 10, wy = (wid >> 5) & 31, wx = wid & 31;
  int wv = tid >> 6, ln = tid & 63;
  int r = ln & 15, q = ln >> 4;

  // ---- P1: stage reflected 12x12 halo, pixel-major xs[t][c]
  {
    short* xs = (short*)(smem + XS_OFF);
    for (int it = tid; it < 13824; it += 256){
      int t = it % 144, c = it / 144;
      int ty = (wy<<3) - 2 + t/12, tx = (wx<<3) - 2 + t%12;
      ty = ty < 0 ? -ty : (ty > 255 ? 510 - ty : ty);
      tx = tx < 0 ? -tx : (tx > 255 ? 510 - tx : tx);
      xs[t*104 + c] = ((const short*)xn2)[(((size_t)(b*96 + c))<<16) + (ty<<8) + tx];
    }
  }
  __syncthreads();

  // ---- P2: Q GEMM (M=96,N=144,K=96) per-wave mt tiles + immediate 5x5 dwconv
  {
    const short* xs = (const short*)(smem + XS_OFF);
    short* Qb = (short*)(smem + QB_OFF) + wv*2368;   // [16][148] shorts
    short* cs = (short*)(smem + CS_OFF);
    int ty0 = (ln>>3)+2, tx0 = (ln&7)+2;
    for (int mt = wv; mt < 6; mt += 4){
      short8v aw[3];
      #pragma unroll
      for (int kt = 0; kt < 3; kt++)
        aw[kt] = ld8<DT>(qw, (size_t)(16*mt + r)*96 + 32*kt + 8*q);
      float qb4[4];
      #pragma unroll
      for (int j = 0; j < 4; j++) qb4[j] = rdf<DT>(qb, 16*mt + 4*q + j);
      for (int nt = 0; nt < 9; nt++){
        f32x4 acc = {0.f,0.f,0.f,0.f};
        #pragma unroll
        for (int kt = 0; kt < 3; kt++){
          short8v bx = *(const short8v*)(xs + (16*nt + r)*104 + 32*kt + 8*q);
          acc = __builtin_amdgcn_mfma_f32_16x16x32_bf16(aw[kt], bx, acc, 0, 0, 0);
        }
        #pragma unroll
        for (int j = 0; j < 4; j++)
          Qb[(4*q+j)*148 + 16*nt + r] = f2bs(acc[j] + qb4[j]);
      }
      asm volatile("s_waitcnt lgkmcnt(0)" ::: "memory");
      for (int cl = 0; cl < 16; cl++){
        int c = 16*mt + cl;
        float a = rdf<DT>(dwb, c);
        #pragma unroll
        for (int dy = -2; dy <= 2; dy++)
          #pragma unroll
          for (int dx = -2; dx <= 2; dx++)
            a += bs2f(Qb[cl*148 + (ty0+dy)*12 + tx0+dx]) * rdf<DT>(dww, c*25 + (dy+2)*5 + dx+2);
        cs[ln*104 + c] = f2bs(a);
      }
      asm volatile("s_waitcnt lgkmcnt(0)" ::: "memory");
    }
  }
  __syncthreads();

  // ---- P3: re-stage centers xc[n][c], then KV GEMM (M=192,N=64,K=96)
  {
    short* xc = (short*)(smem + XC_OFF);
    for (int it = tid; it < 768; it += 256){
      int c = it >> 3, row = it & 7;
      const short* src = (const short*)xn2 + (((size_t)(b*96 + c))<<16)
                         + (((wy<<3)+row)<<8) + (wx<<3);
      short8v v = *(const short8v*)src;
      #pragma unroll
      for (int px = 0; px < 8; px++) xc[(row*8+px)*104 + c] = v[px];
    }
  }
  __syncthreads();
  {
    const short* xc = (const short*)(smem + XC_OFF);
    short* Kt = (short*)(smem + KT_OFF);
    short* Vd = (short*)(smem + VD_OFF);
    for (int mtk = wv; mtk < 12; mtk += 4){
      short8v aw[3];
      #pragma unroll
      for (int kt = 0; kt < 3; kt++)
        aw[kt] = ld8<DT>(kvw, (size_t)(16*mtk + r)*96 + 32*kt + 8*q);
      float bb[4];
      #pragma unroll
      for (int j = 0; j < 4; j++) bb[j] = rdf<DT>(kvb, 16*mtk + 4*q + j);
      for (int nt = 0; nt < 4; nt++){
        f32x4 acc = {0.f,0.f,0.f,0.f};
        #pragma unroll
        for (int kt = 0; kt < 3; kt++){
          short8v bx = *(const short8v*)(xc + (16*nt + r)*104 + 32*kt + 8*q);
          acc = __builtin_amdgcn_mfma_f32_16x16x32_bf16(aw[kt], bx, acc, 0, 0, 0);
        }
        if (mtk < 6){
          short4v kv;
          #pragma unroll
          for (int j = 0; j < 4; j++) kv[j] = f2bs((acc[j] + bb[j]) * SCALE_F);
          *(short4v*)(Kt + (16*nt + r)*104 + 16*mtk + 4*q) = kv;
        } else {
          #pragma unroll
          for (int j = 0; j < 4; j++)
            Vd[(16*(mtk-6) + 4*q + j)*72 + 16*nt + r] = f2bs(acc[j] + bb[j]);
        }
      }
    }
  }
  __syncthreads();

  // ---- P4: attention. Wave wv owns n-tile nt=wv for all 3 heads.
  float o_save[24];
  {
    const short* cs = (const short*)(smem + CS_OFF);
    const short* Kt = (const short*)(smem + KT_OFF);
    const short* Vd = (const short*)(smem + VD_OFF);
    short* Psw = (short*)(smem + PS_OFF) + wv*1152;   // [16][72]
    float lsv = __expf(fminf(rdf<DT>(lsin, 0), LOGIT_MAX_F));
    #pragma unroll
    for (int h = 0; h < 3; h++){
      short8v qa = *(const short8v*)(cs + (16*wv + r)*104 + 32*h + 8*q);
      f32x4 s[4];
      #pragma unroll
      for (int mt = 0; mt < 4; mt++){
        short8v kb = *(const short8v*)(Kt + (16*mt + r)*104 + 32*h + 8*q);
        f32x4 z = {0.f,0.f,0.f,0.f};
        s[mt] = __builtin_amdgcn_mfma_f32_16x16x32_bf16(qa, kb, z, 0, 0, 0);
      }
      float l[4][4];
      #pragma unroll
      for (int mt = 0; mt < 4; mt++){
        float4 bv = *(const float4*)(biasT + h*4096 + (16*mt + r)*64 + 16*wv + 4*q);
        l[mt][0] = s[mt][0]*lsv + bv.x;
        l[mt][1] = s[mt][1]*lsv + bv.y;
        l[mt][2] = s[mt][2]*lsv + bv.z;
        l[mt][3] = s[mt][3]*lsv + bv.w;
      }
      float mx[4], sm[4];
      #pragma unroll
      for (int j = 0; j < 4; j++){
        float m0 = fmaxf(fmaxf(l[0][j], l[1][j]), fmaxf(l[2][j], l[3][j]));
        m0 = fmaxf(m0, __shfl_xor(m0, 1));
        m0 = fmaxf(m0, __shfl_xor(m0, 2));
        m0 = fmaxf(m0, __shfl_xor(m0, 4));
        m0 = fmaxf(m0, __shfl_xor(m0, 8));
        mx[j] = m0; sm[j] = 0.f;
      }
      #pragma unroll
      for (int mt = 0; mt < 4; mt++)
        #pragma unroll
        for (int j = 0; j < 4; j++){
          float p = __expf(l[mt][j] - mx[j]);
          sm[j] += p;
          Psw[(4*q+j)*72 + 16*mt + r] = f2bs(p);
        }
      #pragma unroll
      for (int j = 0; j < 4; j++){
        sm[j] += __shfl_xor(sm[j], 1);
        sm[j] += __shfl_xor(sm[j], 2);
        sm[j] += __shfl_xor(sm[j], 4);
        sm[j] += __shfl_xor(sm[j], 8);
      }
      float inv[4];
      #pragma unroll
      for (int j = 0; j < 4; j++) inv[j] = 1.f / sm[j];
      asm volatile("s_waitcnt lgkmcnt(0)" ::: "memory");
      short8v pa0 = *(const short8v*)(Psw + r*72 + 8*q);
      short8v pa1 = *(const short8v*)(Psw + r*72 + 32 + 8*q);
      #pragma unroll
      for (int dt = 0; dt < 2; dt++){
        f32x4 o = {0.f,0.f,0.f,0.f};
        short8v vb0 = *(const short8v*)(Vd + (32*h + 16*dt + r)*72 + 8*q);
        short8v vb1 = *(const short8v*)(Vd + (32*h + 16*dt + r)*72 + 32 + 8*q);
        o = __builtin_amdgcn_mfma_f32_16x16x32_bf16(pa0, vb0, o, 0, 0, 0);
        o = __builtin_amdgcn_mfma_f32_16x16x32_bf16(pa1, vb1, o, 0, 0, 0);
        #pragma unroll
        for (int j = 0; j < 4; j++) o_save[h*8 + dt*4 + j] = o[j] * inv[j];
      }
      asm volatile("s_waitcnt lgkmcnt(0)" ::: "memory");
    }
  }
  __syncthreads();

  // ---- write osT[n][d] over Kt region
  {
    short* os = (short*)(smem + OS_OFF);
    #pragma unroll
    for (int h = 0; h < 3; h++)
      #pragma unroll
      for (int dt = 0; dt < 2; dt++)
        #pragma unroll
        for (int j = 0; j < 4; j++)
          os[(16*wv + 4*q + j)*104 + 32*h + 16*dt + r] = f2bs(o_save[h*8 + dt*4 + j]);
  }
  __syncthreads();

  // ---- P5: proj GEMM (M=96,N=64,K=96) + residual epilogue
  {
    const short* os = (const short*)(smem + OS_OFF);
    short8v ob[3];
    #pragma unroll
    for (int kt = 0; kt < 3; kt++)
      ob[kt] = *(const short8v*)(os + (16*wv + r)*104 + 32*kt + 8*q);
    for (int mt = 0; mt < 6; mt++){
      f32x4 acc = {0.f,0.f,0.f,0.f};
      #pragma unroll
      for (int kt = 0; kt < 3; kt++){
        short8v aw = ld8<DT>(pw, (size_t)(16*mt + r)*96 + 32*kt + 8*q);
        acc = __builtin_amdgcn_mfma_f32_16x16x32_bf16(aw, ob[kt], acc, 0, 0, 0);
      }
      #pragma unroll
      for (int j = 0; j < 4; j++){
        int oc = 16*mt + 4*q + j;
        int n  = 16*wv + r;
        int gy = (wy<<3) + (n>>3), gx = (wx<<3) + (n&7);
        size_t gi = (((size_t)(b*96 + oc))<<16) + (gy<<8) + gx;
        float a = acc[j] + rdf<DT>(pb, oc);
        float x1 = rdf<DT>(xin, gi) + a*stats[8 + b*96 + oc] + stats[392 + b*96 + oc];
        wrf<DT>(outp, gi, x1);
      }
    }
  }
}

// ---------- K6: MFMA MLP v2, N-blocked ----------
// Block = 256 contiguous pixels, 4 waves; wave owns 64 pixels (4 n-tiles of 16).
// Weight fragments amortized over 4 n-tiles (144 loads : 576 MFMAs per wave).
// GEMM1 (h-slice of 32) and GEMM2 partial-accumulate are interleaved per t so H
// never materializes; H fragments use the round-0-validated k-permutation pack.
template<int DT>
__global__ __launch_bounds__(256) void k_mlp_mfma(void* __restrict__ io,
    const void* w1, const void* b1, const void* w2, const void* b2v,
    const int* __restrict__ flag){
  if (*flag != DT) return;
  __shared__ __align__(16) short x1s[256*104];   // [pixel][channel], 53248 B
  int blk = blockIdx.x; int b = blk >> 8; int pix0 = (blk & 255) << 8;
  int tid = threadIdx.x;

  // stage X: coalesced global (512B per wave-instr pair), transposed LDS write
  for (int c = 0; c < 96; c++){
    size_t gi = (((size_t)(b*96 + c))<<16) + pix0 + tid;
    short v = DT ? f2bs(((const float*)io)[gi]) : ((const short*)io)[gi];
    x1s[tid*104 + c] = v;
  }
  __syncthreads();

  int wv = tid >> 6, l = tid & 63;
  int r = l & 15, q = l >> 4;
  int pbase = wv << 6;                   // wave's 64-pixel base within tile

  f32x4 acc2[6][4];
  #pragma unroll
  for (int mt = 0; mt < 6; mt++)
    #pragma unroll
    for (int nt = 0; nt < 4; nt++)
      acc2[mt][nt] = (f32x4){0.f,0.f,0.f,0.f};

  #pragma unroll 2
  for (int t = 0; t < 12; t++){
    // GEMM1 weights for h-rows [32t, 32t+32)
    short8v aA[3], aB[3];
    #pragma unroll
    for (int kt = 0; kt < 3; kt++){
      aA[kt] = ld8<DT>(w1, (size_t)(32*t + r)*96      + 32*kt + 8*q);
      aB[kt] = ld8<DT>(w1, (size_t)(32*t + 16 + r)*96 + 32*kt + 8*q);
    }
    float bA[4], bB[4];
    #pragma unroll
    for (int j = 0; j < 4; j++){
      bA[j] = rdf<DT>(b1, 32*t + 4*q + j);
      bB[j] = rdf<DT>(b1, 32*t + 16 + 4*q + j);
    }
    // GEMM1: 4 n-tiles share the weight fragments
    f32x4 a1A[4], a1B[4];
    #pragma unroll
    for (int nt = 0; nt < 4; nt++){
      a1A[nt] = (f32x4){0.f,0.f,0.f,0.f};
      a1B[nt] = (f32x4){0.f,0.f,0.f,0.f};
    }
    #pragma unroll
    for (int kt = 0; kt < 3; kt++){
      #pragma unroll
      for (int nt = 0; nt < 4; nt++){
        short8v bx = *(const short8v*)&x1s[(pbase + 16*nt + r)*104 + 32*kt + 8*q];
        a1A[nt] = __builtin_amdgcn_mfma_f32_16x16x32_bf16(aA[kt], bx, a1A[nt], 0, 0, 0);
        a1B[nt] = __builtin_amdgcn_mfma_f32_16x16x32_bf16(aB[kt], bx, a1B[nt], 0, 0, 0);
      }
    }
    // pack H fragments (bias + relu), then GEMM2 partial accumulate for this t
    short8v B2[4];
    #pragma unroll
    for (int nt = 0; nt < 4; nt++){
      short8v h;
      #pragma unroll
      for (int j = 0; j < 4; j++){
        h[j]   = f2bs(fmaxf(a1A[nt][j] + bA[j], 0.f));  // H[32t+4q+j][px]
        h[4+j] = f2bs(fmaxf(a1B[nt][j] + bB[j], 0.f));  // H[32t+16+4q+j][px]
      }
      B2[nt] = h;
    }
    #pragma unroll
    for (int mt = 0; mt < 6; mt++){
      short8v wA = ld4x2<DT>(w2, (size_t)(16*mt + r)*384 + 32*t + 4*q);
      #pragma unroll
      for (int nt = 0; nt < 4; nt++)
        acc2[mt][nt] = __builtin_amdgcn_mfma_f32_16x16x32_bf16(wA, B2[nt], acc2[mt][nt], 0, 0, 0);
    }
  }

  // epilogue: bias + residual + store.  bf16 residual comes from LDS (exact bits);
  // fp32 residual must stay exact -> global read.
  #pragma unroll
  for (int mt = 0; mt < 6; mt++)
    #pragma unroll
    for (int nt = 0; nt < 4; nt++)
      #pragma unroll
      for (int j = 0; j < 4; j++){
        int oc = 16*mt + 4*q + j;
        int pl = pbase + 16*nt + r;
        size_t gi = (((size_t)(b*96 + oc))<<16) + pix0 + pl;
        float v = acc2[mt][nt][j] + rdf<DT>(b2v, oc);
        if (DT){
          ((float*)io)[gi] = ((const float*)io)[gi] + v;
        } else {
          ((bf16*)io)[gi] = f2b(bs2f(x1s[pl*104 + oc]) + v);
        }
      }
}

extern "C" void kernel_launch(void* const* d_in, const int* in_sizes, int n_in,
                              void* d_out, int out_size, void* d_ws, size_t ws_size,
                              hipStream_t stream) {
  const void* x      = d_in[0];
  const void* agnw   = d_in[1];
  const void* agnb   = d_in[2];
  const void* meta1w = d_in[3];
  const void* meta1b = d_in[4];
  const void* meta2w = d_in[5];
  const void* meta2b = d_in[6];
  const void* la1w   = d_in[7];
  const void* la1b   = d_in[8];
  const void* la2w   = d_in[9];
  const void* la2b   = d_in[10];
  const void* ta1w   = d_in[11];
  const void* ta1b   = d_in[12];
  const void* ta2w   = d_in[13];
  const void* ta2b   = d_in[14];
  const void* qw     = d_in[15];
  const void* qb     = d_in[16];
  const void* kvw    = d_in[17];
  const void* kvb    = d_in[18];
  const void* dww    = d_in[19];
  const void* dwb    = d_in[20];
  const void* pw     = d_in[21];
  const void* pb     = d_in[22];
  const void* lsin   = d_in[23];
  const void* rpw1   = d_in[24];
  const void* rpb1   = d_in[25];
  const void* rpw2   = d_in[26];
  const void* rpb2   = d_in[27];
  const void* m1w    = d_in[28];
  const void* m1b    = d_in[29];
  const void* m2w    = d_in[30];
  const void* m2b    = d_in[31];

  // ws: flag @0 | partials @256 | stats @8448 | biasT @12288 | xn2 @65536 (48MB)
  char* ws = (char*)d_ws;
  int*   flag     = (int*)ws;
  float* partials = (float*)(ws + 256);
  float* stats    = (float*)(ws + 8448);
  float* biasT    = (float*)(ws + 12288);
  bf16*  xn2      = (bf16*)(ws + 65536);

  k_detect<<<1, 256, 0, stream>>>(x, flag);

  // bf16 variant
  k_stats_partial<0><<<1024, 256, 0, stream>>>(x, partials, flag);
  k_stats_final<0>  <<<1,    256, 0, stream>>>(partials, meta1w, meta1b, meta2w, meta2b, stats, flag);
  k_bias<0>         <<<4096, 256, 0, stream>>>(rpw1, rpb1, rpw2, rpb2, biasT, flag);
  k_agn_fused<0>    <<<98304,256, 0, stream>>>(x, stats, la1w, la1b, la2w, la2b,
                                               ta1w, ta1b, ta2w, ta2b, agnw, agnb, xn2, flag);
  k_attn_mega<0>    <<<4096, 256, 0, stream>>>(xn2, qw, qb, kvw, kvb, dww, dwb, pw, pb,
                                               lsin, biasT, x, stats, d_out, flag);
  k_mlp_mfma<0>     <<<1024, 256, 0, stream>>>(d_out, m1w, m1b, m2w, m2b, flag);

  // fp32 variant
  k_stats_partial<1><<<1024, 256, 0, stream>>>(x, partials, flag);
  k_stats_final<1>  <<<1,    256, 0, stream>>>(partials, meta1w, meta1b, meta2w, meta2b, stats, flag);
  k_bias<1>         <<<4096, 256, 0, stream>>>(rpw1, rpb1, rpw2, rpb2, biasT, flag);
  k_agn_fused<1>    <<<98304,256, 0, stream>>>(x, stats, la1w, la1b, la2w, la2b,
                                               ta1w, ta1b, ta2w, ta2b, agnw, agnb, xn2, flag);
  k_attn_mega<1>    <<<4096, 256, 0, stream>>>(xn2, qw, qb, kvw, kvb, dww, dwb, pw, pb,
                                               lsin, biasT, x, stats, d_out, flag);
  k_mlp_mfma<1>     <<<1024, 256, 0, stream>>>(d_out, m1w, m1b, m2w, m2b, flag);
}

// Round 4
// 1106.856 us; speedup vs baseline: 2.9366x; 1.0290x over previous
//
#include <hip/hip_runtime.h>
#include <hip/hip_bf16.h>

typedef __hip_bfloat16 bf16;

#define PER_B     6291456            // 96*65536
#define EPS_F     1e-5f
#define SCALE_F   0.17677669529663687f   // 32^-0.5
#define LOGIT_MAX_F 4.605170185988092f   // log(100)

__device__ __forceinline__ float b2f(bf16 v){ return __bfloat162float(v); }
__device__ __forceinline__ bf16  f2b(float v){ return __float2bfloat16(v); }

// DT=0: buffers are bf16.  DT=1: buffers are fp32.
template<int DT> __device__ __forceinline__ float rdf(const void* p, size_t i){
  return DT ? ((const float*)p)[i] : b2f(((const bf16*)p)[i]);
}
template<int DT> __device__ __forceinline__ void wrf(void* p, size_t i, float v){
  if (DT) ((float*)p)[i] = v; else ((bf16*)p)[i] = f2b(v);
}
// paired weight load (i must be even)
template<int DT> __device__ __forceinline__ float2 rd2(const void* p, size_t i){
  if (DT) return *(const float2*)((const float*)p + i);
  unsigned u = *(const unsigned*)((const bf16*)p + i);
  return make_float2(__uint_as_float(u << 16), __uint_as_float(u & 0xffff0000u));
}

// ---------- MFMA helpers ----------
typedef __attribute__((ext_vector_type(8))) short short8v;   // 8 bf16 (4 VGPRs)
typedef __attribute__((ext_vector_type(4))) short short4v;
typedef __attribute__((ext_vector_type(4))) float f32x4;

// fp32 -> bf16 bits, round-to-nearest-even (finite inputs)
__device__ __forceinline__ short f2bs(float v){
  unsigned u = __float_as_uint(v);
  return (short)((u + 0x7fffu + ((u >> 16) & 1u)) >> 16);
}
__device__ __forceinline__ float bs2f(short s){
  return __uint_as_float(((unsigned)(unsigned short)s) << 16);
}

// load 8 contiguous weights (elements i..i+8) as bf16 bits; i % 8 == 0
template<int DT> __device__ __forceinline__ short8v ld8(const void* p, size_t i){
  short8v a;
  if (DT){
    const float* f = (const float*)p + i;
    float4 lo = *(const float4*)f;
    float4 hi = *(const float4*)(f + 4);
    a[0]=f2bs(lo.x); a[1]=f2bs(lo.y); a[2]=f2bs(lo.z); a[3]=f2bs(lo.w);
    a[4]=f2bs(hi.x); a[5]=f2bs(hi.y); a[6]=f2bs(hi.z); a[7]=f2bs(hi.w);
  } else {
    a = *(const short8v*)((const short*)p + i);
  }
  return a;
}
// load two 4-element chunks at i0 and i0+16 (elements); i0 % 4 == 0
template<int DT> __device__ __forceinline__ short8v ld4x2(const void* p, size_t i0){
  short8v a;
  if (DT){
    const float* f = (const float*)p;
    float4 lo = *(const float4*)(f + i0);
    float4 hi = *(const float4*)(f + i0 + 16);
    a[0]=f2bs(lo.x); a[1]=f2bs(lo.y); a[2]=f2bs(lo.z); a[3]=f2bs(lo.w);
    a[4]=f2bs(hi.x); a[5]=f2bs(hi.y); a[6]=f2bs(hi.z); a[7]=f2bs(hi.w);
  } else {
    const short* s = (const short*)p;
    short4v lo = *(const short4v*)(s + i0);
    short4v hi = *(const short4v*)(s + i0 + 16);
    a[0]=lo[0]; a[1]=lo[1]; a[2]=lo[2]; a[3]=lo[3];
    a[4]=hi[0]; a[5]=hi[1]; a[6]=hi[2]; a[7]=hi[3];
  }
  return a;
}

// ---------- K0: dtype detector ----------
__global__ __launch_bounds__(256) void k_detect(const void* __restrict__ x, int* __restrict__ flag){
  __shared__ int cnt;
  if (threadIdx.x == 0) cnt = 0;
  __syncthreads();
  float v = b2f(((const bf16*)x)[(size_t)threadIdx.x * 16]);
  int bad = (!(v == v)) || (fabsf(v) > 1e20f);
  if (bad) atomicAdd(&cnt, 1);
  __syncthreads();
  if (threadIdx.x == 0) *flag = (cnt >= 4) ? 1 : 0;
}

// ---------- K1: per-batch partial sums ----------
template<int DT>
__global__ __launch_bounds__(256) void k_stats_partial(const void* __restrict__ x,
    float* __restrict__ partials, const int* __restrict__ flag){
  if (*flag != DT) return;
  int blk = blockIdx.x;
  int b = blk >> 8, chunk = blk & 255;
  const int chunkN = PER_B / 256;
  size_t base = (size_t)b * PER_B + (size_t)chunk * chunkN;
  float s = 0.f, ss = 0.f;
  for (int i = threadIdx.x; i < chunkN; i += 256){
    float v = rdf<DT>(x, base + i); s += v; ss += v*v;
  }
  __shared__ float sh[512];
  sh[threadIdx.x] = s; sh[256 + threadIdx.x] = ss;
  __syncthreads();
  for (int st = 128; st > 0; st >>= 1){
    if (threadIdx.x < st){
      sh[threadIdx.x]     += sh[threadIdx.x + st];
      sh[256+threadIdx.x] += sh[256+threadIdx.x + st];
    }
    __syncthreads();
  }
  if (threadIdx.x == 0){ partials[blk*2] = sh[0]; partials[blk*2+1] = sh[256]; }
}

// ---------- K2: finalize mean/std + rescale/rebias ----------
template<int DT>
__global__ __launch_bounds__(256) void k_stats_final(const float* __restrict__ partials,
    const void* m1w, const void* m1b, const void* m2w, const void* m2b,
    float* __restrict__ stats, const int* __restrict__ flag){
  if (*flag != DT) return;
  __shared__ float sh[512];
  __shared__ float mS[4], sS[4];
  for (int b = 0; b < 4; b++){
    sh[threadIdx.x]     = partials[(b*256+threadIdx.x)*2];
    sh[256+threadIdx.x] = partials[(b*256+threadIdx.x)*2+1];
    __syncthreads();
    for (int st = 128; st > 0; st >>= 1){
      if (threadIdx.x < st){
        sh[threadIdx.x]     += sh[threadIdx.x + st];
        sh[256+threadIdx.x] += sh[256+threadIdx.x + st];
      }
      __syncthreads();
    }
    if (threadIdx.x == 0){
      float mean = sh[0] / (float)PER_B;
      float var  = sh[256] / (float)PER_B - mean*mean;
      float stdv = sqrtf(var + EPS_F);
      mS[b] = mean; sS[b] = stdv;
      stats[b] = mean; stats[4+b] = stdv;
    }
    __syncthreads();
  }
  for (int t = threadIdx.x; t < 384; t += 256){
    int b = t / 96, c = t % 96;
    stats[8+t]   = sS[b]*rdf<DT>(m1w,c) + rdf<DT>(m1b,c);
    stats[392+t] = mS[b]*rdf<DT>(m2w,c) + rdf<DT>(m2b,c);
  }
}

// ---------- K3: rel-pos bias table, transposed [h][m][n] ----------
template<int DT>
__global__ __launch_bounds__(256) void k_bias(const void* w1, const void* b1v,
    const void* w2, const void* b2v, float* __restrict__ biasT, const int* __restrict__ flag){
  if (*flag != DT) return;
  int i = blockIdx.x >> 6, j = blockIdx.x & 63;   // i = query n, j = key m
  int dy = (i>>3) - (j>>3), dx = (i&7) - (j&7);
  float fy = (float)dy, fx = (float)dx;
  float r0 = copysignf(log1pf(fabsf(fy)), fy);
  float r1 = copysignf(log1pf(fabsf(fx)), fx);
  int t = threadIdx.x;
  float hb = fmaxf(r0*rdf<DT>(w1,t*2) + r1*rdf<DT>(w1,t*2+1) + rdf<DT>(b1v,t), 0.f);
  __shared__ float sh[256];
  for (int h = 0; h < 3; h++){
    sh[t] = hb * rdf<DT>(w2, h*256+t);
    __syncthreads();
    for (int st = 128; st > 0; st >>= 1){ if (t < st) sh[t] += sh[t+st]; __syncthreads(); }
    if (t == 0) biasT[h*4096 + j*64 + i] = sh[0] + rdf<DT>(b2v, h);
    __syncthreads();
  }
}

// ---------- K4: fused AGN: x -> xn2 (bf16) ----------
template<int DT>
__global__ __launch_bounds__(256) void k_agn_fused(const void* __restrict__ x,
    const float* __restrict__ stats,
    const void* la1w, const void* la1b, const void* la2w, const void* la2b,
    const void* ta1w, const void* ta1b, const void* ta2w, const void* ta2b,
    const void* agnw, const void* agnb,
    bf16* __restrict__ xn2, const int* __restrict__ flag){
  if (*flag != DT) return;
  __shared__ float xs[400];   // 20x20 zero-padded
  __shared__ float ts[324];   // 18x18
  __shared__ float us[324];
  int idx = blockIdx.x;
  int tile = idx & 255; int bc = idx >> 8; int c = bc % 96; int b = bc / 96;
  int oy = (tile >> 4) << 4, ox = (tile & 15) << 4;
  float mean = stats[b], sd = stats[4+b];
  size_t xbase = ((size_t)bc) << 16;
  for (int it = threadIdx.x; it < 400; it += 256){
    int ly = it / 20, lx = it % 20;
    int gy = oy - 2 + ly, gx = ox - 2 + lx;
    float v = 0.f;
    if (gy >= 0 && gy < 256 && gx >= 0 && gx < 256)
      v = (rdf<DT>(x, xbase + (gy<<8) + gx) - mean) / sd;
    xs[it] = v;
  }
  float wl1[9], wt1[9], wl2[9], wt2[9];
  #pragma unroll
  for (int k = 0; k < 9; k++){
    wl1[k] = rdf<DT>(la1w, c*9+k); wt1[k] = rdf<DT>(ta1w, c*9+k);
    wl2[k] = rdf<DT>(la2w, c*9+k); wt2[k] = rdf<DT>(ta2w, c*9+k);
  }
  float bl1 = rdf<DT>(la1b, c), bt1 = rdf<DT>(ta1b, c);
  __syncthreads();
  for (int it = threadIdx.x; it < 324; it += 256){
    int ly = it / 18, lx = it % 18;
    int cy = oy - 1 + ly, cx = ox - 1 + lx;
    float a1 = 0.f, a2 = 0.f;
    if (cy >= 0 && cy < 256 && cx >= 0 && cx < 256){
      a1 = bl1; a2 = bt1;
      #pragma unroll
      for (int dy = 0; dy < 3; dy++)
        #pragma unroll
        for (int dx = 0; dx < 3; dx++){
          float v = xs[(ly+dy)*20 + lx+dx];
          a1 += v * wl1[dy*3+dx]; a2 += v * wt1[dy*3+dx];
        }
      a1 = fmaxf(a1, 0.f); a2 = fmaxf(a2, 0.f);
    }
    ts[it] = a1; us[it] = a2;
  }
  __syncthreads();
  int ty = threadIdx.x >> 4, tx0 = threadIdx.x & 15;
  float l = rdf<DT>(la2b, c), t = rdf<DT>(ta2b, c);
  #pragma unroll
  for (int dy = 0; dy < 3; dy++)
    #pragma unroll
    for (int dx = 0; dx < 3; dx++){
      l += ts[(ty+dy)*18 + tx0+dx] * wl2[dy*3+dx];
      t += us[(ty+dy)*18 + tx0+dx] * wt2[dy*3+dx];
    }
  float v = xs[(ty+2)*20 + tx0+2];
  float r = v*(rdf<DT>(agnw,c)*stats[8+bc]) + (rdf<DT>(agnb,c) + stats[392+bc]) + l + t;
  xn2[xbase + ((oy+ty)<<8) + ox + tx0] = f2b(r);
}

// ---------- K5: MFMA mega window kernel, 3 blocks/CU ----------
// LDS arena 53760 B, overlaid regions (all transitions barrier-separated):
//  CS @0      short[64][104]  = 13312  (P2-P4)  conv-q, [n][c]
//  XS @13312  short[144][104] = 29952  (P1-P2)  halo, [t][c]
//  QB @43264  short[8][148] x4 waves = 9472 (P2)  per-wave half-Q scratch
//  KT @13312  short[64][104]  = 13312  (P3-P4)  K, [m][d], pre-scaled (over XS)
//  VD @26624  short[96][72]   = 13824  (P3-P4)  V, [d][m] (over XS)
//  XC @40448  short[64][104]  = 13312  (P3)     centers [n][c] (over XS/QB tail)
//  PS @40448  short[16][72] x4 waves = 9216 (P4)  per-wave P scratch (over XC)
//  OS @13312  short[64][104]  = 13312  (P5)     attn out [n][d] (over KT)
#define CS_OFF 0
#define XS_OFF 13312
#define QB_OFF 43264
#define KT_OFF 13312
#define VD_OFF 26624
#define XC_OFF 40448
#define PS_OFF 40448
#define OS_OFF 13312

template<int DT>
__global__ __launch_bounds__(256, 3) void k_attn_mega(const bf16* __restrict__ xn2,
    const void* qw, const void* qb, const void* kvw, const void* kvb,
    const void* dww, const void* dwb, const void* pw, const void* pb,
    const void* lsin, const float* __restrict__ biasT,
    const void* __restrict__ xin, const float* __restrict__ stats,
    void* __restrict__ outp, const int* __restrict__ flag){
  if (*flag != DT) return;
  __shared__ __align__(16) char smem[53760];
  int tid = threadIdx.x, wid = blockIdx.x;
  int b = wid >> 10, wy = (wid >> 5) & 31, wx = wid & 31;
  int wv = tid >> 6, ln = tid & 63;
  int r = ln & 15, q = ln >> 4;

  // ---- P1: stage reflected 12x12 halo, pixel-major xs[t][c].
  // Lane->channel assignment XORed by (t>>3)&7: spreads the 52-dword-stride
  // column writes from 8-way to ~2-way bank conflict; layout stays standard.
  {
    short* xs = (short*)(smem + XS_OFF);
    for (int it = tid; it < 13824; it += 256){
      int t = it % 144, craw = it / 144;
      int c = craw ^ ((t >> 3) & 7);
      int ty = (wy<<3) - 2 + t/12, tx = (wx<<3) - 2 + t%12;
      ty = ty < 0 ? -ty : (ty > 255 ? 510 - ty : ty);
      tx = tx < 0 ? -tx : (tx > 255 ? 510 - tx : tx);
      xs[t*104 + c] = ((const short*)xn2)[(((size_t)(b*96 + c))<<16) + (ty<<8) + tx];
    }
  }
  __syncthreads();

  // ---- P2: Q GEMM (M=96,N=144,K=96) + 5x5 dwconv, half-QB (8 ch) scratch.
  // 16-row MFMA output kept in regs (accs[9][4]); written+convolved in two
  // 8-channel halves so per-wave scratch is [8][148] instead of [16][148].
  {
    const short* xs = (const short*)(smem + XS_OFF);
    short* Qb = (short*)(smem + QB_OFF) + wv*1184;   // [8][148] shorts
    short* cs = (short*)(smem + CS_OFF);
    int ty0 = (ln>>3)+2, tx0 = (ln&7)+2;
    for (int mt = wv; mt < 6; mt += 4){
      short8v aw[3];
      #pragma unroll
      for (int kt = 0; kt < 3; kt++)
        aw[kt] = ld8<DT>(qw, (size_t)(16*mt + r)*96 + 32*kt + 8*q);
      float qb4[4];
      #pragma unroll
      for (int j = 0; j < 4; j++) qb4[j] = rdf<DT>(qb, 16*mt + 4*q + j);
      float accs[9][4];
      #pragma unroll
      for (int nt = 0; nt < 9; nt++){
        f32x4 acc = {0.f,0.f,0.f,0.f};
        #pragma unroll
        for (int kt = 0; kt < 3; kt++){
          short8v bx = *(const short8v*)(xs + (16*nt + r)*104 + 32*kt + 8*q);
          acc = __builtin_amdgcn_mfma_f32_16x16x32_bf16(aw[kt], bx, acc, 0, 0, 0);
        }
        #pragma unroll
        for (int j = 0; j < 4; j++) accs[nt][j] = acc[j] + qb4[j];
      }
      // half A: rows 0..7 (lanes q<2)
      if (q < 2){
        #pragma unroll
        for (int nt = 0; nt < 9; nt++)
          #pragma unroll
          for (int j = 0; j < 4; j++)
            Qb[(4*q+j)*148 + 16*nt + r] = f2bs(accs[nt][j]);
      }
      asm volatile("s_waitcnt lgkmcnt(0)" ::: "memory");
      for (int cl = 0; cl < 8; cl++){
        int c = 16*mt + cl;
        float a = rdf<DT>(dwb, c);
        #pragma unroll
        for (int dy = -2; dy <= 2; dy++)
          #pragma unroll
          for (int dx = -2; dx <= 2; dx++)
            a += bs2f(Qb[cl*148 + (ty0+dy)*12 + tx0+dx]) * rdf<DT>(dww, c*25 + (dy+2)*5 + dx+2);
        cs[ln*104 + c] = f2bs(a);
      }
      asm volatile("s_waitcnt lgkmcnt(0)" ::: "memory");
      // half B: rows 8..15 (lanes q>=2)
      if (q >= 2){
        #pragma unroll
        for (int nt = 0; nt < 9; nt++)
          #pragma unroll
          for (int j = 0; j < 4; j++)
            Qb[(4*(q-2)+j)*148 + 16*nt + r] = f2bs(accs[nt][j]);
      }
      asm volatile("s_waitcnt lgkmcnt(0)" ::: "memory");
      for (int cl = 8; cl < 16; cl++){
        int c = 16*mt + cl;
        float a = rdf<DT>(dwb, c);
        #pragma unroll
        for (int dy = -2; dy <= 2; dy++)
          #pragma unroll
          for (int dx = -2; dx <= 2; dx++)
            a += bs2f(Qb[(cl-8)*148 + (ty0+dy)*12 + tx0+dx]) * rdf<DT>(dww, c*25 + (dy+2)*5 + dx+2);
        cs[ln*104 + c] = f2bs(a);
      }
      asm volatile("s_waitcnt lgkmcnt(0)" ::: "memory");
    }
  }
  __syncthreads();

  // ---- P3: re-stage centers xc[n][c] (px^row write order: 16-way -> 2-way),
  //          then KV GEMM (M=192,N=64,K=96)
  {
    short* xc = (short*)(smem + XC_OFF);
    for (int it = tid; it < 768; it += 256){
      int c = it >> 3, row = it & 7;
      const short* src = (const short*)xn2 + (((size_t)(b*96 + c))<<16)
                         + (((wy<<3)+row)<<8) + (wx<<3);
      short8v v = *(const short8v*)src;
      #pragma unroll
      for (int k = 0; k < 8; k++){
        int pe = k ^ row;
        xc[(row*8+pe)*104 + c] = v[pe];
      }
    }
  }
  __syncthreads();
  {
    const short* xc = (const short*)(smem + XC_OFF);
    short* Kt = (short*)(smem + KT_OFF);
    short* Vd = (short*)(smem + VD_OFF);
    for (int mtk = wv; mtk < 12; mtk += 4){
      short8v aw[3];
      #pragma unroll
      for (int kt = 0; kt < 3; kt++)
        aw[kt] = ld8<DT>(kvw, (size_t)(16*mtk + r)*96 + 32*kt + 8*q);
      float bb[4];
      #pragma unroll
      for (int j = 0; j < 4; j++) bb[j] = rdf<DT>(kvb, 16*mtk + 4*q + j);
      for (int nt = 0; nt < 4; nt++){
        f32x4 acc = {0.f,0.f,0.f,0.f};
        #pragma unroll
        for (int kt = 0; kt < 3; kt++){
          short8v bx = *(const short8v*)(xc + (16*nt + r)*104 + 32*kt + 8*q);
          acc = __builtin_amdgcn_mfma_f32_16x16x32_bf16(aw[kt], bx, acc, 0, 0, 0);
        }
        if (mtk < 6){
          short4v kv;
          #pragma unroll
          for (int j = 0; j < 4; j++) kv[j] = f2bs((acc[j] + bb[j]) * SCALE_F);
          *(short4v*)(Kt + (16*nt + r)*104 + 16*mtk + 4*q) = kv;
        } else {
          #pragma unroll
          for (int j = 0; j < 4; j++)
            Vd[(16*(mtk-6) + 4*q + j)*72 + 16*nt + r] = f2bs(acc[j] + bb[j]);
        }
      }
    }
  }
  __syncthreads();

  // ---- P4: attention. Wave wv owns n-tile nt=wv for all 3 heads.
  float o_save[24];
  {
    const short* cs = (const short*)(smem + CS_OFF);
    const short* Kt = (const short*)(smem + KT_OFF);
    const short* Vd = (const short*)(smem + VD_OFF);
    short* Psw = (short*)(smem + PS_OFF) + wv*1152;   // [16][72]
    float lsv = __expf(fminf(rdf<DT>(lsin, 0), LOGIT_MAX_F));
    #pragma unroll
    for (int h = 0; h < 3; h++){
      short8v qa = *(const short8v*)(cs + (16*wv + r)*104 + 32*h + 8*q);
      f32x4 s[4];
      #pragma unroll
      for (int mt = 0; mt < 4; mt++){
        short8v kb = *(const short8v*)(Kt + (16*mt + r)*104 + 32*h + 8*q);
        f32x4 z = {0.f,0.f,0.f,0.f};
        s[mt] = __builtin_amdgcn_mfma_f32_16x16x32_bf16(qa, kb, z, 0, 0, 0);
      }
      float l[4][4];
      #pragma unroll
      for (int mt = 0; mt < 4; mt++){
        float4 bv = *(const float4*)(biasT + h*4096 + (16*mt + r)*64 + 16*wv + 4*q);
        l[mt][0] = s[mt][0]*lsv + bv.x;
        l[mt][1] = s[mt][1]*lsv + bv.y;
        l[mt][2] = s[mt][2]*lsv + bv.z;
        l[mt][3] = s[mt][3]*lsv + bv.w;
      }
      float mx[4], sm[4];
      #pragma unroll
      for (int j = 0; j < 4; j++){
        float m0 = fmaxf(fmaxf(l[0][j], l[1][j]), fmaxf(l[2][j], l[3][j]));
        m0 = fmaxf(m0, __shfl_xor(m0, 1));
        m0 = fmaxf(m0, __shfl_xor(m0, 2));
        m0 = fmaxf(m0, __shfl_xor(m0, 4));
        m0 = fmaxf(m0, __shfl_xor(m0, 8));
        mx[j] = m0; sm[j] = 0.f;
      }
      #pragma unroll
      for (int mt = 0; mt < 4; mt++)
        #pragma unroll
        for (int j = 0; j < 4; j++){
          float p = __expf(l[mt][j] - mx[j]);
          sm[j] += p;
          Psw[(4*q+j)*72 + 16*mt + r] = f2bs(p);
        }
      #pragma unroll
      for (int j = 0; j < 4; j++){
        sm[j] += __shfl_xor(sm[j], 1);
        sm[j] += __shfl_xor(sm[j], 2);
        sm[j] += __shfl_xor(sm[j], 4);
        sm[j] += __shfl_xor(sm[j], 8);
      }
      float inv[4];
      #pragma unroll
      for (int j = 0; j < 4; j++) inv[j] = 1.f / sm[j];
      asm volatile("s_waitcnt lgkmcnt(0)" ::: "memory");
      short8v pa0 = *(const short8v*)(Psw + r*72 + 8*q);
      short8v pa1 = *(const short8v*)(Psw + r*72 + 32 + 8*q);
      #pragma unroll
      for (int dt = 0; dt < 2; dt++){
        f32x4 o = {0.f,0.f,0.f,0.f};
        short8v vb0 = *(const short8v*)(Vd + (32*h + 16*dt + r)*72 + 8*q);
        short8v vb1 = *(const short8v*)(Vd + (32*h + 16*dt + r)*72 + 32 + 8*q);
        o = __builtin_amdgcn_mfma_f32_16x16x32_bf16(pa0, vb0, o, 0, 0, 0);
        o = __builtin_amdgcn_mfma_f32_16x16x32_bf16(pa1, vb1, o, 0, 0, 0);
        #pragma unroll
        for (int j = 0; j < 4; j++) o_save[h*8 + dt*4 + j] = o[j] * inv[j];
      }
      asm volatile("s_waitcnt lgkmcnt(0)" ::: "memory");
    }
  }
  __syncthreads();

  // ---- write osT[n][d] over KT region
  {
    short* os = (short*)(smem + OS_OFF);
    #pragma unroll
    for (int h = 0; h < 3; h++)
      #pragma unroll
      for (int dt = 0; dt < 2; dt++)
        #pragma unroll
        for (int j = 0; j < 4; j++)
          os[(16*wv + 4*q + j)*104 + 32*h + 16*dt + r] = f2bs(o_save[h*8 + dt*4 + j]);
  }
  __syncthreads();

  // ---- P5: proj GEMM (M=96,N=64,K=96) + residual epilogue
  {
    const short* os = (const short*)(smem + OS_OFF);
    short8v ob[3];
    #pragma unroll
    for (int kt = 0; kt < 3; kt++)
      ob[kt] = *(const short8v*)(os + (16*wv + r)*104 + 32*kt + 8*q);
    for (int mt = 0; mt < 6; mt++){
      f32x4 acc = {0.f,0.f,0.f,0.f};
      #pragma unroll
      for (int kt = 0; kt < 3; kt++){
        short8v aw = ld8<DT>(pw, (size_t)(16*mt + r)*96 + 32*kt + 8*q);
        acc = __builtin_amdgcn_mfma_f32_16x16x32_bf16(aw, ob[kt], acc, 0, 0, 0);
      }
      #pragma unroll
      for (int j = 0; j < 4; j++){
        int oc = 16*mt + 4*q + j;
        int n  = 16*wv + r;
        int gy = (wy<<3) + (n>>3), gx = (wx<<3) + (n&7);
        size_t gi = (((size_t)(b*96 + oc))<<16) + (gy<<8) + gx;
        float a = acc[j] + rdf<DT>(pb, oc);
        float x1 = rdf<DT>(xin, gi) + a*stats[8 + b*96 + oc] + stats[392 + b*96 + oc];
        wrf<DT>(outp, gi, x1);
      }
    }
  }
}

// ---------- K6: MFMA MLP v2, N-blocked ----------
template<int DT>
__global__ __launch_bounds__(256) void k_mlp_mfma(void* __restrict__ io,
    const void* w1, const void* b1, const void* w2, const void* b2v,
    const int* __restrict__ flag){
  if (*flag != DT) return;
  __shared__ __align__(16) short x1s[256*104];   // [pixel][channel], 53248 B
  int blk = blockIdx.x; int b = blk >> 8; int pix0 = (blk & 255) << 8;
  int tid = threadIdx.x;

  for (int c = 0; c < 96; c++){
    size_t gi = (((size_t)(b*96 + c))<<16) + pix0 + tid;
    short v = DT ? f2bs(((const float*)io)[gi]) : ((const short*)io)[gi];
    x1s[tid*104 + c] = v;
  }
  __syncthreads();

  int wv = tid >> 6, l = tid & 63;
  int r = l & 15, q = l >> 4;
  int pbase = wv << 6;

  f32x4 acc2[6][4];
  #pragma unroll
  for (int mt = 0; mt < 6; mt++)
    #pragma unroll
    for (int nt = 0; nt < 4; nt++)
      acc2[mt][nt] = (f32x4){0.f,0.f,0.f,0.f};

  #pragma unroll 2
  for (int t = 0; t < 12; t++){
    short8v aA[3], aB[3];
    #pragma unroll
    for (int kt = 0; kt < 3; kt++){
      aA[kt] = ld8<DT>(w1, (size_t)(32*t + r)*96      + 32*kt + 8*q);
      aB[kt] = ld8<DT>(w1, (size_t)(32*t + 16 + r)*96 + 32*kt + 8*q);
    }
    float bA[4], bB[4];
    #pragma unroll
    for (int j = 0; j < 4; j++){
      bA[j] = rdf<DT>(b1, 32*t + 4*q + j);
      bB[j] = rdf<DT>(b1, 32*t + 16 + 4*q + j);
    }
    f32x4 a1A[4], a1B[4];
    #pragma unroll
    for (int nt = 0; nt < 4; nt++){
      a1A[nt] = (f32x4){0.f,0.f,0.f,0.f};
      a1B[nt] = (f32x4){0.f,0.f,0.f,0.f};
    }
    #pragma unroll
    for (int kt = 0; kt < 3; kt++){
      #pragma unroll
      for (int nt = 0; nt < 4; nt++){
        short8v bx = *(const short8v*)&x1s[(pbase + 16*nt + r)*104 + 32*kt + 8*q];
        a1A[nt] = __builtin_amdgcn_mfma_f32_16x16x32_bf16(aA[kt], bx, a1A[nt], 0, 0, 0);
        a1B[nt] = __builtin_amdgcn_mfma_f32_16x16x32_bf16(aB[kt], bx, a1B[nt], 0, 0, 0);
      }
    }
    short8v B2[4];
    #pragma unroll
    for (int nt = 0; nt < 4; nt++){
      short8v h;
      #pragma unroll
      for (int j = 0; j < 4; j++){
        h[j]   = f2bs(fmaxf(a1A[nt][j] + bA[j], 0.f));
        h[4+j] = f2bs(fmaxf(a1B[nt][j] + bB[j], 0.f));
      }
      B2[nt] = h;
    }
    #pragma unroll
    for (int mt = 0; mt < 6; mt++){
      short8v wA = ld4x2<DT>(w2, (size_t)(16*mt + r)*384 + 32*t + 4*q);
      #pragma unroll
      for (int nt = 0; nt < 4; nt++)
        acc2[mt][nt] = __builtin_amdgcn_mfma_f32_16x16x32_bf16(wA, B2[nt], acc2[mt][nt], 0, 0, 0);
    }
  }

  #pragma unroll
  for (int mt = 0; mt < 6; mt++)
    #pragma unroll
    for (int nt = 0; nt < 4; nt++)
      #pragma unroll
      for (int j = 0; j < 4; j++){
        int oc = 16*mt + 4*q + j;
        int pl = pbase + 16*nt + r;
        size_t gi = (((size_t)(b*96 + oc))<<16) + pix0 + pl;
        float v = acc2[mt][nt][j] + rdf<DT>(b2v, oc);
        if (DT){
          ((float*)io)[gi] = ((const float*)io)[gi] + v;
        } else {
          ((bf16*)io)[gi] = f2b(bs2f(x1s[pl*104 + oc]) + v);
        }
      }
}

extern "C" void kernel_launch(void* const* d_in, const int* in_sizes, int n_in,
                              void* d_out, int out_size, void* d_ws, size_t ws_size,
                              hipStream_t stream) {
  const void* x      = d_in[0];
  const void* agnw   = d_in[1];
  const void* agnb   = d_in[2];
  const void* meta1w = d_in[3];
  const void* meta1b = d_in[4];
  const void* meta2w = d_in[5];
  const void* meta2b = d_in[6];
  const void* la1w   = d_in[7];
  const void* la1b   = d_in[8];
  const void* la2w   = d_in[9];
  const void* la2b   = d_in[10];
  const void* ta1w   = d_in[11];
  const void* ta1b   = d_in[12];
  const void* ta2w   = d_in[13];
  const void* ta2b   = d_in[14];
  const void* qw     = d_in[15];
  const void* qb     = d_in[16];
  const void* kvw    = d_in[17];
  const void* kvb    = d_in[18];
  const void* dww    = d_in[19];
  const void* dwb    = d_in[20];
  const void* pw     = d_in[21];
  const void* pb     = d_in[22];
  const void* lsin   = d_in[23];
  const void* rpw1   = d_in[24];
  const void* rpb1   = d_in[25];
  const void* rpw2   = d_in[26];
  const void* rpb2   = d_in[27];
  const void* m1w    = d_in[28];
  const void* m1b    = d_in[29];
  const void* m2w    = d_in[30];
  const void* m2b    = d_in[31];

  // ws: flag @0 | partials @256 | stats @8448 | biasT @12288 | xn2 @65536 (48MB)
  char* ws = (char*)d_ws;
  int*   flag     = (int*)ws;
  float* partials = (float*)(ws + 256);
  float* stats    = (float*)(ws + 8448);
  float* biasT    = (float*)(ws + 12288);
  bf16*  xn2      = (bf16*)(ws + 65536);

  k_detect<<<1, 256, 0, stream>>>(x, flag);

  // bf16 variant
  k_stats_partial<0><<<1024, 256, 0, stream>>>(x, partials, flag);
  k_stats_final<0>  <<<1,    256, 0, stream>>>(partials, meta1w, meta1b, meta2w, meta2b, stats, flag);
  k_bias<0>         <<<4096, 256, 0, stream>>>(rpw1, rpb1, rpw2, rpb2, biasT, flag);
  k_agn_fused<0>    <<<98304,256, 0, stream>>>(x, stats, la1w, la1b, la2w, la2b,
                                               ta1w, ta1b, ta2w, ta2b, agnw, agnb, xn2, flag);
  k_attn_mega<0>    <<<4096, 256, 0, stream>>>(xn2, qw, qb, kvw, kvb, dww, dwb, pw, pb,
                                               lsin, biasT, x, stats, d_out, flag);
  k_mlp_mfma<0>     <<<1024, 256, 0, stream>>>(d_out, m1w, m1b, m2w, m2b, flag);

  // fp32 variant
  k_stats_partial<1><<<1024, 256, 0, stream>>>(x, partials, flag);
  k_stats_final<1>  <<<1,    256, 0, stream>>>(partials, meta1w, meta1b, meta2w, meta2b, stats, flag);
  k_bias<1>         <<<4096, 256, 0, stream>>>(rpw1, rpb1, rpw2, rpb2, biasT, flag);
  k_agn_fused<1>    <<<98304,256, 0, stream>>>(x, stats, la1w, la1b, la2w, la2b,
                                               ta1w, ta1b, ta2w, ta2b, agnw, agnb, xn2, flag);
  k_attn_mega<1>    <<<4096, 256, 0, stream>>>(xn2, qw, qb, kvw, kvb, dww, dwb, pw, pb,
                                               lsin, biasT, x, stats, d_out, flag);
  k_mlp_mfma<1>     <<<1024, 256, 0, stream>>>(d_out, m1w, m1b, m2w, m2b, flag);
}